// Round 8
// baseline (1369.402 us; speedup 1.0000x reference)
//
#include <hip/hip_runtime.h>
#include <hip/hip_cooperative_groups.h>
#include <math.h>

namespace cg = cooperative_groups;

#define EPS_NORM 1e-5f
#define EPS_VAR  1e-9f
#define LOG2E    1.4426950408889634f

typedef unsigned short ushort_t;
typedef __attribute__((ext_vector_type(4))) float f32x4;
typedef _Float16 half8 __attribute__((ext_vector_type(8)));

#define MFMAH(a, b, c) __builtin_amdgcn_mfma_f32_16x16x32_f16((a), (b), (c), 0, 0, 0)

#define GLD16(gp, lp) __builtin_amdgcn_global_load_lds(                          \
    (const __attribute__((address_space(1))) unsigned int*)(gp),                 \
    (__attribute__((address_space(3))) unsigned int*)(lp), 16, 0, 0)

// ---------------------------------------------------------------------------
// fp16 helpers
// ---------------------------------------------------------------------------
__device__ inline ushort_t f16_bits(float x) {
    _Float16 h = (_Float16)x;
    ushort_t u;
    __builtin_memcpy(&u, &h, 2);
    return u;
}
__device__ inline half8 ldh(const ushort_t* p) {
    half8 h;
    __builtin_memcpy(&h, p, 16);
    return h;
}
__device__ inline uint4 pack8(const ushort_t* s) {
    uint4 r;
    r.x = (unsigned)s[0] | ((unsigned)s[1] << 16);
    r.y = (unsigned)s[2] | ((unsigned)s[3] << 16);
    r.z = (unsigned)s[4] | ((unsigned)s[5] << 16);
    r.w = (unsigned)s[6] | ((unsigned)s[7] << 16);
    return r;
}

// ---------------------------------------------------------------------------
// Stats: float4-vectorized (4 channels x 32 rows per thread, 16B/lane)
// ---------------------------------------------------------------------------
struct StatJobs4 {
    const float* x[9];
    float* sm[9];
    float* sq[9];
    int N[9], Cn[9], cG[9], nG[9], base[9];   // cG = ceil(Cn/256)
};
__device__ __forceinline__ void stat_body(const StatJobs4& J, int bx)
{
    int j = 0;
#pragma unroll
    for (int k = 1; k < 9; ++k) if (bx >= J.base[k]) j = k;
    bx -= J.base[j];
    const int N = J.N[j], Cn = J.Cn[j], cG = J.cG[j], nG = J.nG[j];
    const int b   = bx / (cG * nG);
    const int r   = bx % (cG * nG);
    const int cgi = r / nG;
    const int ng  = r % nG;
    const int lane = threadIdx.x & 63, wv = threadIdx.x >> 6;
    const int c4 = cgi * 64 + lane;            // float4 index
    if (c4 * 4 >= Cn) return;
    const int n0 = ng * 128 + wv * 32;
    if (n0 >= N) return;
    const int n1 = min(n0 + 32, N);
    const int c4s = Cn >> 2;
    const float4* p = (const float4*)(J.x[j] + (long)(b * N) * Cn) + (long)n0 * c4s + c4;
    float4 s  = {0.f, 0.f, 0.f, 0.f};
    float4 ss = {0.f, 0.f, 0.f, 0.f};
    for (int n = n0; n < n1; ++n) {
        float4 v = *p;
        p += c4s;
        s.x += v.x; s.y += v.y; s.z += v.z; s.w += v.w;
        ss.x = fmaf(v.x, v.x, ss.x); ss.y = fmaf(v.y, v.y, ss.y);
        ss.z = fmaf(v.z, v.z, ss.z); ss.w = fmaf(v.w, v.w, ss.w);
    }
    float* smp = J.sm[j] + b * Cn + c4 * 4;
    float* sqp = J.sq[j] + b * Cn + c4 * 4;
#pragma unroll
    for (int e = 0; e < 4; ++e) {
        atomicAdd(&smp[e], (&s.x)[e]);
        atomicAdd(&sqp[e], (&ss.x)[e]);
    }
}
__global__ void __launch_bounds__(256) stat_partial_all(StatJobs4 J)
{
    stat_body(J, (int)blockIdx.x);
}

// finalize kept ONLY for the scalar fallback path
struct FinJobs {
    float* sm[9];
    float* sq[9];
    int base[9];
    float invN[9];
    int total;
};
__global__ void __launch_bounds__(256) stat_finalize_all(FinJobs J)
{
    int i = blockIdx.x * 256 + threadIdx.x;
    if (i >= J.total) return;
    int j = 0;
#pragma unroll
    for (int k = 1; k < 9; ++k) if (i >= J.base[k]) j = k;
    int e = i - J.base[j];
    float m = J.sm[j][e] * J.invN[j];
    float v = J.sq[j][e] * J.invN[j] - m * m;
    J.sm[j][e] = m;
    J.sq[j][e] = rsqrtf(v + EPS_NORM);
}

// ---------------------------------------------------------------------------
// norm (inline finalize, wave-per-row, float4) and V-transpose via LDS tile.
// ---------------------------------------------------------------------------
__device__ __forceinline__ void norm_quad(
    int bx, const float* __restrict__ qx, const float* __restrict__ qs,
    const float* __restrict__ qq, const float* __restrict__ kx,
    const float* __restrict__ ks, const float* __restrict__ kq,
    ushort_t* __restrict__ qh, ushort_t* __restrict__ kh,
    int N, int Cc, float invN)
{
    const int wave = threadIdx.x >> 6, lane = threadIdx.x & 63;
    int rr = bx * 4 + wave;
    const int BN = 4 * N;
    const bool isQ = rr < BN;
    int bn = isQ ? rr : rr - BN;
    const float* x  = isQ ? qx : kx;
    const float* sm = isQ ? qs : ks;
    const float* sq = isQ ? qq : kq;
    ushort_t* out   = isQ ? qh : kh;
    const float scl = isQ ? LOG2E : 1.0f;
    int b = bn / N;
    long base = (long)bn * Cc;
    const float* smb = sm + b * Cc;
    const float* sqb = sq + b * Cc;
    for (int c8 = lane; c8 * 8 < Cc; c8 += 64) {
        int ch = c8 * 8;
        float4 a0 = *(const float4*)(x + base + ch);
        float4 a1 = *(const float4*)(x + base + ch + 4);
        float4 s0 = *(const float4*)(smb + ch);
        float4 s1 = *(const float4*)(smb + ch + 4);
        float4 t0 = *(const float4*)(sqb + ch);
        float4 t1 = *(const float4*)(sqb + ch + 4);
        ushort_t h8[8];
#pragma unroll
        for (int e = 0; e < 4; ++e) {
            float m = (&s0.x)[e] * invN;
            float r = rsqrtf((&t0.x)[e] * invN - m * m + EPS_NORM);
            h8[e] = f16_bits(((&a0.x)[e] - m) * r * scl);
        }
#pragma unroll
        for (int e = 0; e < 4; ++e) {
            float m = (&s1.x)[e] * invN;
            float r = rsqrtf((&t1.x)[e] * invN - m * m + EPS_NORM);
            h8[4 + e] = f16_bits(((&a1.x)[e] - m) * r * scl);
        }
        *(uint4*)(out + base + ch) = pack8(h8);
    }
}

__device__ __forceinline__ void vtile(
    int bid2, const float* __restrict__ vx, ushort_t* __restrict__ vt,
    int N, int C, ushort_t* tbuf)
{
    const int cT = C >> 6, nT = N >> 6;
    int b   = bid2 / (cT * nT);
    int rem = bid2 % (cT * nT);
    int ch0 = (rem / nT) << 6;
    int n0  = (rem % nT) << 6;
    const int lane = threadIdx.x & 63, wv = threadIdx.x >> 6;
    const float* vb_ = vx + (long)b * N * C + ch0 + lane;
#pragma unroll
    for (int jj = 0; jj < 2; ++jj) {
        int nl = wv * 16 + jj * 8;
        ushort_t h8[8];
#pragma unroll
        for (int i = 0; i < 8; ++i)
            h8[i] = f16_bits(vb_[(long)(n0 + nl + i) * C]);
        *(uint4*)&tbuf[lane * 72 + nl] = pack8(h8);
    }
    __syncthreads();
    {
        const int chl = threadIdx.x >> 2;
        const int nq  = (threadIdx.x & 3) * 16;
        ushort_t* op = vt + ((long)b * C + ch0 + chl) * N + n0 + nq;
        *(uint4*)op       = *(const uint4*)&tbuf[chl * 72 + nq];
        *(uint4*)(op + 8) = *(const uint4*)&tbuf[chl * 72 + nq + 8];
    }
}

// ---------------------------------------------------------------------------
// Async DMA tile stagers.  LDS tiles 64 shorts/row, XOR-swizzled.
// ---------------------------------------------------------------------------
__device__ inline void stage64_async(const ushort_t* __restrict__ g, long rowBase,
                                     int gstride, int col0, ushort_t* slab, int tid)
{
    const int l  = tid & 63, w = tid >> 6;
    const int rs = l >> 3;
    const int cg = (l & 7) ^ rs;
#pragma unroll
    for (int i = 0; i < 2; ++i) {
        const int r = w * 16 + i * 8 + rs;
        const ushort_t* gp = g + (rowBase + r) * (long)gstride + col0 + (cg << 3);
        ushort_t* lp = slab + (w * 16 + i * 8) * 64 + l * 8;
        GLD16(gp, lp);
    }
}
template<int BROWS>
__device__ inline void stageQ_async(const ushort_t* __restrict__ g, long rowBase,
                                    int gstride, int col0, ushort_t* slab, int tid)
{
    if (tid < BROWS * 8) {
        const int l  = tid & 63, w = tid >> 6;
        const int rs = l >> 3;
        const int cg = (l & 7) ^ rs;
        const int r  = w * 8 + rs;
        const ushort_t* gp = g + (rowBase + r) * (long)gstride + col0 + (cg << 3);
        ushort_t* lp = slab + w * 8 * 64 + l * 8;
        GLD16(gp, lp);
    }
}
__device__ inline half8 ldsw(const ushort_t* slab, int row, int soff)
{
    const int gr = (soff >> 3) ^ (row & 7);
    return ldh(slab + row * 64 + (gr << 3));
}

// ---------------------------------------------------------------------------
// Flash scale 2 body (12-phase pipeline; proven 243 us) — device fn form.
// ---------------------------------------------------------------------------
__device__ __forceinline__ void flash2_body(
    const ushort_t* __restrict__ Qh, const ushort_t* __restrict__ Kh,
    const ushort_t* __restrict__ Vth,
    float* __restrict__ Pmo, float* __restrict__ Plo,
    float* __restrict__ PMo, float* __restrict__ PSo,
    ushort_t* smem, int bid)
{
    constexpr int Cc = 448, C = 256, N = 4096, SPLIT = 2;
    constexpr int NKT  = (N / 64) / SPLIT;
    constexpr long VCHO = 64L * N;
    constexpr long KADV = 64L * Cc;

    const int tid  = threadIdx.x;
    const int lane = tid & 63;
    const int w    = tid >> 6;
    const int l15  = lane & 15;
    const int quad = lane >> 4;

    const int grp = bid & 7;
    const int sp  = grp & 1;
    const int b   = grp >> 1;
    const int qb  = bid >> 3;
    const int i0 = qb * 64 + w * 16;
    const long po = (long)(b * (N / 16) + qb * 4 + w) * SPLIT + sp;

    const int rs    = lane >> 3;
    const int cg    = (lane & 7) ^ rs;
    const int ldso0 = w * 1024 + lane * 8;
    const int ldso1 = ldso0 + 512;
    const int xh    = l15 & 7;
    const int lb0   = l15 * 64 + ((quad)     ^ xh) * 8;
    const int lb1   = l15 * 64 + ((4 + quad) ^ xh) * 8;
    ushort_t* const Pw  = smem + 32768 + w * 1152;
    ushort_t* const pww = Pw + quad * 288 + l15;
    const ushort_t* const pfr = Pw + l15 * 72 + quad * 8;

    const long krow0 = (long)b * N + (long)sp * NKT * 64;
    const ushort_t* kp0 = Kh + (krow0 + w * 16 + rs) * (long)Cc + (cg << 3);
    const ushort_t* kp1 = kp0 + 8 * Cc;
    const ushort_t* vp0 = Vth + ((long)b * C + w * 16 + rs) * (long)N
                              + (cg << 3) + (long)sp * NKT * 64;
    const ushort_t* vp1 = vp0 + 8 * (long)N;

#define SLOT(k) (smem + (k) * 8192)
#define STGKP(c0, c1, slot, toff) do {                                           \
    GLD16(kp0 + (toff) + (c0) * 64, SLOT(slot) + ldso0);                         \
    GLD16(kp1 + (toff) + (c0) * 64, SLOT(slot) + ldso1);                         \
    GLD16(kp0 + (toff) + (c1) * 64, SLOT(slot) + 4096 + ldso0);                  \
    GLD16(kp1 + (toff) + (c1) * 64, SLOT(slot) + 4096 + ldso1); } while (0)
#define STGK1(c0, slot, toff) do {                                               \
    GLD16(kp0 + (toff) + (c0) * 64, SLOT(slot) + ldso0);                         \
    GLD16(kp1 + (toff) + (c0) * 64, SLOT(slot) + ldso1); } while (0)
#define STGVP(j0, slot, voff) do {                                               \
    GLD16(vp0 + (voff) + (j0) * VCHO, SLOT(slot) + ldso0);                       \
    GLD16(vp1 + (voff) + (j0) * VCHO, SLOT(slot) + ldso1);                       \
    GLD16(vp0 + (voff) + ((j0) + 1) * VCHO, SLOT(slot) + 4096 + ldso0);          \
    GLD16(vp1 + (voff) + ((j0) + 1) * VCHO, SLOT(slot) + 4096 + ldso1); } while (0)

#define WAITV(NN) asm volatile("s_waitcnt vmcnt(" #NN ")" ::: "memory");         \
    __builtin_amdgcn_sched_barrier(0);                                           \
    __builtin_amdgcn_s_barrier();                                                \
    __builtin_amdgcn_s_setprio(1);
#define PH_END __builtin_amdgcn_s_setprio(0);

#define QKPAIR(slot, c0) do {                                                    \
    const ushort_t* s0_ = SLOT(slot);                                            \
    const ushort_t* s1_ = s0_ + 4096;                                            \
    _Pragma("unroll")                                                            \
    for (int ct = 0; ct < 4; ++ct) S[ct] = MFMAH(qf[2*(c0)+0], ldh(s0_ + ct*1024 + lb0), S[ct]); \
    _Pragma("unroll")                                                            \
    for (int ct = 0; ct < 4; ++ct) S[ct] = MFMAH(qf[2*(c0)+1], ldh(s0_ + ct*1024 + lb1), S[ct]); \
    _Pragma("unroll")                                                            \
    for (int ct = 0; ct < 4; ++ct) S[ct] = MFMAH(qf[2*(c0)+2], ldh(s1_ + ct*1024 + lb0), S[ct]); \
    _Pragma("unroll")                                                            \
    for (int ct = 0; ct < 4; ++ct) S[ct] = MFMAH(qf[2*(c0)+3], ldh(s1_ + ct*1024 + lb1), S[ct]); } while (0)
#define QK1(slot, c0) do {                                                       \
    const ushort_t* s0_ = SLOT(slot);                                            \
    _Pragma("unroll")                                                            \
    for (int ct = 0; ct < 4; ++ct) S[ct] = MFMAH(qf[2*(c0)+0], ldh(s0_ + ct*1024 + lb0), S[ct]); \
    _Pragma("unroll")                                                            \
    for (int ct = 0; ct < 4; ++ct) S[ct] = MFMAH(qf[2*(c0)+1], ldh(s0_ + ct*1024 + lb1), S[ct]); } while (0)
#define PVPAIR(slot, ci0) do {                                                   \
    const ushort_t* s0_ = SLOT(slot);                                            \
    const ushort_t* s1_ = s0_ + 4096;                                            \
    _Pragma("unroll")                                                            \
    for (int ct = 0; ct < 4; ++ct) {                                             \
        half8 vh = ldh(s0_ + ct*1024 + lb0); half8 uh = vh * vh;                 \
        Mac[(ci0)*4 + ct] = MFMAH(pf0, vh, Mac[(ci0)*4 + ct]);                   \
        Sac[(ci0)*4 + ct] = MFMAH(pf0, uh, Sac[(ci0)*4 + ct]); }                 \
    _Pragma("unroll")                                                            \
    for (int ct = 0; ct < 4; ++ct) {                                             \
        half8 vh = ldh(s0_ + ct*1024 + lb1); half8 uh = vh * vh;                 \
        Mac[(ci0)*4 + ct] = MFMAH(pf1, vh, Mac[(ci0)*4 + ct]);                   \
        Sac[(ci0)*4 + ct] = MFMAH(pf1, uh, Sac[(ci0)*4 + ct]); }                 \
    _Pragma("unroll")                                                            \
    for (int ct = 0; ct < 4; ++ct) {                                             \
        half8 vh = ldh(s1_ + ct*1024 + lb0); half8 uh = vh * vh;                 \
        Mac[(ci0+1)*4 + ct] = MFMAH(pf0, vh, Mac[(ci0+1)*4 + ct]);               \
        Sac[(ci0+1)*4 + ct] = MFMAH(pf0, uh, Sac[(ci0+1)*4 + ct]); }             \
    _Pragma("unroll")                                                            \
    for (int ct = 0; ct < 4; ++ct) {                                             \
        half8 vh = ldh(s1_ + ct*1024 + lb1); half8 uh = vh * vh;                 \
        Mac[(ci0+1)*4 + ct] = MFMAH(pf1, vh, Mac[(ci0+1)*4 + ct]);               \
        Sac[(ci0+1)*4 + ct] = MFMAH(pf1, uh, Sac[(ci0+1)*4 + ct]); } } while (0)
#define RESET_S do {                                                             \
    _Pragma("unroll")                                                            \
    for (int ct = 0; ct < 4; ++ct)                                               \
        _Pragma("unroll")                                                        \
        for (int r = 0; r < 4; ++r) S[ct][r] = 0.f; } while (0)

    half8 qf[14];
    {
        const ushort_t* q1 = Qh + ((long)(b * N + i0 + l15)) * Cc + quad * 8;
#pragma unroll
        for (int ks = 0; ks < 14; ++ks) qf[ks] = ldh(q1 + ks * 32);
    }
    asm volatile("s_waitcnt vmcnt(0)" ::: "memory");

    float m_r[4], l_l[4], mw = -1e30f;
    f32x4 Mac[16], Sac[16];
    f32x4 S[4];
    half8 pf0, pf1;
#pragma unroll
    for (int r = 0; r < 4; ++r) { m_r[r] = -1e30f; l_l[r] = 0.f; }
#pragma unroll
    for (int ct = 0; ct < 16; ++ct)
#pragma unroll
        for (int r = 0; r < 4; ++r) { Mac[ct][r] = 0.f; Sac[ct][r] = 0.f; }

    auto softmax_step = [&]() {
        float tmax = S[0][0];
#pragma unroll
        for (int ct = 0; ct < 4; ++ct)
#pragma unroll
            for (int r = 0; r < 4; ++r) tmax = fmaxf(tmax, S[ct][r]);
#pragma unroll
        for (int off = 1; off <= 32; off <<= 1)
            tmax = fmaxf(tmax, __shfl_xor(tmax, off, 64));

        if (tmax > mw + 14.4269504f) {
            float rm[4];
#pragma unroll
            for (int r = 0; r < 4; ++r)
                rm[r] = fmaxf(fmaxf(S[0][r], S[1][r]), fmaxf(S[2][r], S[3][r]));
#pragma unroll
            for (int off = 1; off <= 8; off <<= 1)
#pragma unroll
                for (int r = 0; r < 4; ++r)
                    rm[r] = fmaxf(rm[r], __shfl_xor(rm[r], off, 64));
#pragma unroll
            for (int r = 0; r < 4; ++r) {
                float mn = fmaxf(m_r[r], rm[r]);
                float corr = exp2f(m_r[r] - mn);
                m_r[r] = mn;
                l_l[r] *= corr;
#pragma unroll
                for (int ct = 0; ct < 16; ++ct) { Mac[ct][r] *= corr; Sac[ct][r] *= corr; }
            }
            float tt = fminf(fminf(m_r[0], m_r[1]), fminf(m_r[2], m_r[3]));
            tt = fminf(tt, __shfl_xor(tt, 16, 64));
            tt = fminf(tt, __shfl_xor(tt, 32, 64));
            mw = tt;
        }
#pragma unroll
        for (int ct = 0; ct < 4; ++ct)
#pragma unroll
            for (int r = 0; r < 4; ++r) {
                float p = exp2f(S[ct][r] - m_r[r]);
                l_l[r] += p;
                pww[r * 72 + ct * 16] = f16_bits(p);
            }
        pf0 = ldh(pfr);
        pf1 = ldh(pfr + 32);
    };

    STGKP(0, 1, 0, 0);
    STGKP(2, 3, 1, 0);

    for (int it = 0; it < NKT / 2; ++it) {
        RESET_S;
        STGKP(4, 5, 2, 0);
        WAITV(8)  QKPAIR(0, 0); PH_END;
        STGK1(6, 3, 0);
        WAITV(6)  QKPAIR(1, 2); PH_END;
        STGVP(0, 0, 0);
        WAITV(6)  QKPAIR(2, 4); PH_END;
        STGVP(2, 1, 0);
        WAITV(8)  QK1(3, 6); PH_END;
        softmax_step();
        STGKP(0, 1, 2, KADV);
        WAITV(8)  PVPAIR(0, 0); PH_END;
        STGKP(2, 3, 3, KADV);
        WAITV(8)  PVPAIR(1, 2); PH_END;

        RESET_S;
        STGKP(4, 5, 0, KADV);
        WAITV(8)  QKPAIR(2, 0); PH_END;
        STGK1(6, 1, KADV);
        WAITV(6)  QKPAIR(3, 2); PH_END;
        STGVP(0, 2, 64);
        WAITV(6)  QKPAIR(0, 4); PH_END;
        STGVP(2, 3, 64);
        WAITV(8)  QK1(1, 6); PH_END;
        softmax_step();
        const bool more = (it + 1 < NKT / 2);
        if (more) {
            kp0 += 2 * KADV; kp1 += 2 * KADV;
            STGKP(0, 1, 0, 0);
            asm volatile("s_waitcnt vmcnt(8)" ::: "memory");
        } else {
            asm volatile("s_waitcnt vmcnt(4)" ::: "memory");
        }
        __builtin_amdgcn_sched_barrier(0);
        __builtin_amdgcn_s_barrier();
        __builtin_amdgcn_s_setprio(1);
        PVPAIR(2, 0);
        PH_END;
        if (more) {
            STGKP(2, 3, 1, 0);
            asm volatile("s_waitcnt vmcnt(8)" ::: "memory");
        } else {
            asm volatile("s_waitcnt vmcnt(0)" ::: "memory");
        }
        __builtin_amdgcn_sched_barrier(0);
        __builtin_amdgcn_s_barrier();
        __builtin_amdgcn_s_setprio(1);
        PVPAIR(3, 2);
        PH_END;

        vp0 += 128; vp1 += 128;
    }
#undef SLOT
#undef STGKP
#undef STGK1
#undef STGVP
#undef WAITV
#undef PH_END
#undef QKPAIR
#undef QK1
#undef PVPAIR
#undef RESET_S

#pragma unroll
    for (int off = 1; off <= 8; off <<= 1)
#pragma unroll
        for (int r = 0; r < 4; ++r) l_l[r] += __shfl_xor(l_l[r], off, 64);

    if (l15 == 0) {
#pragma unroll
        for (int r = 0; r < 4; ++r) {
            Pmo[po * 16 + quad * 4 + r] = m_r[r];
            Plo[po * 16 + quad * 4 + r] = l_l[r];
        }
    }
#pragma unroll
    for (int ct = 0; ct < 16; ++ct)
#pragma unroll
        for (int r = 0; r < 4; ++r) {
            long idx = (po * 16 + quad * 4 + r) * C + ct * 16 + l15;
            PMo[idx] = Mac[ct][r];
            PSo[idx] = Sac[ct][r];
        }
}

__global__ void __launch_bounds__(256, 2) flash_pipe(
    const ushort_t* __restrict__ Qh, const ushort_t* __restrict__ Kh,
    const ushort_t* __restrict__ Vth,
    float* __restrict__ Pmo, float* __restrict__ Plo,
    float* __restrict__ PMo, float* __restrict__ PSo)
{
    __shared__ __align__(16) ushort_t smem[37376];
    flash2_body(Qh, Kh, Vth, Pmo, Plo, PMo, PSo, smem, (int)blockIdx.x);
}

// ---------------------------------------------------------------------------
// Generic flash body (scales 3/4): QK chunk-split + S-merge (round-6 proven).
// ---------------------------------------------------------------------------
template<int Cc, int C, int N, int CSPLIT, bool QREG, int SPLIT, int SLABS, int KGRP>
__device__ __forceinline__ void flash_body(
    const ushort_t* __restrict__ Qh, const ushort_t* __restrict__ Kh,
    const ushort_t* __restrict__ Vth,
    float* __restrict__ Pmo, float* __restrict__ Plo,
    float* __restrict__ PMo, float* __restrict__ PSo,
    ushort_t* smem, int bid)
{
    constexpr int KC      = Cc / 64;
    constexpr int VC      = C / 64;
    constexpr int VCW     = VC / CSPLIT;
    constexpr int CTCW    = 4 * VCW;
    constexpr int STRIPES = 4 / CSPLIT;
    constexpr int BROWS   = 16 * STRIPES;
    constexpr int QB      = N / BROWS;
    constexpr int TILES   = N / 64;
    constexpr int NKT     = TILES / SPLIT;
    constexpr int NKS     = QREG ? (Cc / 32) : 1;
    constexpr int NGRP    = (KC + KGRP - 1) / KGRP;
    constexpr int G       = 4 / CSPLIT;
    constexpr int QCH     = BROWS * 64;
    constexpr int QOFF    = KGRP * 4096;
    constexpr int KQEND   = QOFF + KGRP * QCH;
    constexpr int REGION  = QREG ? (SLABS * 4096)
                                 : (KQEND > SLABS * 4096 ? KQEND : SLABS * 4096);

    const int tid  = threadIdx.x;
    const int lane = tid & 63;
    const int w    = tid >> 6;
    const int l15  = lane & 15;
    const int quad = lane >> 4;

    const int bq = bid / SPLIT;
    const int sp = bid % SPLIT;
    const int b  = bq / QB;
    const int qb = bq % QB;
    const int ls  = w / CSPLIT;
    const int ch2 = w % CSPLIT;
    const int i0 = qb * BROWS + ls * 16;
    const long po = (long)(b * (N / 16) + qb * STRIPES + ls) * SPLIT + sp;
    ushort_t* Pw = smem + REGION + w * 1152;

    half8 qf[NKS];
    if constexpr (QREG) {
        const ushort_t* q1 = Qh + ((long)(b * N + i0 + l15)) * Cc + quad * 8;
#pragma unroll
        for (int ks = 0; ks < NKS; ++ks) qf[ks] = ldh(q1 + ks * 32);
    }

    float m_r[4], l_l[4], mw = -1e30f;
    f32x4 Mac[CTCW], Sac[CTCW];
#pragma unroll
    for (int r = 0; r < 4; ++r) { m_r[r] = -1e30f; l_l[r] = 0.f; }
#pragma unroll
    for (int ct = 0; ct < CTCW; ++ct)
#pragma unroll
        for (int r = 0; r < 4; ++r) { Mac[ct][r] = 0.f; Sac[ct][r] = 0.f; }

    for (int kt = sp * NKT; kt < sp * NKT + NKT; ++kt) {
        const long krow = (long)b * N + kt * 64;

        f32x4 S[4];
#pragma unroll
        for (int ct = 0; ct < 4; ++ct)
#pragma unroll
            for (int r = 0; r < 4; ++r) S[ct][r] = 0.f;

#pragma unroll
        for (int grp = 0; grp < NGRP; ++grp) {
            const int g0 = grp * KGRP;
            const int gn = (KC - g0 < KGRP) ? (KC - g0) : KGRP;
            __syncthreads();
#pragma unroll
            for (int j = 0; j < KGRP; ++j) if (j < gn) {
                stage64_async(Kh, krow, Cc, (g0 + j) * 64, smem + j * 4096, tid);
                if constexpr (!QREG)
                    stageQ_async<BROWS>(Qh, (long)b * N + qb * BROWS, Cc, (g0 + j) * 64,
                                        smem + QOFF + j * QCH, tid);
            }
            __syncthreads();
#pragma unroll
            for (int j = 0; j < KGRP; ++j) if (j < gn) {
                if (((g0 + j) % CSPLIT) == ch2) {
#pragma unroll
                    for (int ks = 0; ks < 2; ++ks) {
                        half8 a;
                        if constexpr (QREG) a = qf[(g0 + j) * 2 + ks];
                        else a = ldsw(smem + QOFF + j * QCH, ls * 16 + l15, ks * 32 + quad * 8);
#pragma unroll
                        for (int ct = 0; ct < 4; ++ct) {
                            half8 bf = ldsw(smem + j * 4096, ct * 16 + l15, ks * 32 + quad * 8);
                            S[ct] = MFMAH(a, bf, S[ct]);
                        }
                    }
                }
            }
        }

        if constexpr (CSPLIT > 1) {
            float* sred = (float*)smem;
            __syncthreads();
#pragma unroll
            for (int ct = 0; ct < 4; ++ct)
                *(f32x4*)&sred[(w * 4 + ct) * 256 + lane * 4] = S[ct];
            __syncthreads();
#pragma unroll
            for (int p = 0; p < 4; ++p) {
                if (p == w) continue;
                if ((p / CSPLIT) != ls) continue;
#pragma unroll
                for (int ct = 0; ct < 4; ++ct) {
                    f32x4 t = *(const f32x4*)&sred[(p * 4 + ct) * 256 + lane * 4];
                    S[ct] = S[ct] + t;
                }
            }
        }

        float tmax = S[0][0];
#pragma unroll
        for (int ct = 0; ct < 4; ++ct)
#pragma unroll
            for (int r = 0; r < 4; ++r) tmax = fmaxf(tmax, S[ct][r]);
#pragma unroll
        for (int off = 1; off <= 32; off <<= 1)
            tmax = fmaxf(tmax, __shfl_xor(tmax, off, 64));

        if (tmax > mw + 14.4269504f) {
            float rm[4];
#pragma unroll
            for (int r = 0; r < 4; ++r)
                rm[r] = fmaxf(fmaxf(S[0][r], S[1][r]), fmaxf(S[2][r], S[3][r]));
#pragma unroll
            for (int off = 1; off <= 8; off <<= 1)
#pragma unroll
                for (int r = 0; r < 4; ++r)
                    rm[r] = fmaxf(rm[r], __shfl_xor(rm[r], off, 64));
#pragma unroll
            for (int r = 0; r < 4; ++r) {
                float mn = fmaxf(m_r[r], rm[r]);
                float corr = exp2f(m_r[r] - mn);
                m_r[r] = mn;
                l_l[r] *= corr;
#pragma unroll
                for (int ct = 0; ct < CTCW; ++ct) { Mac[ct][r] *= corr; Sac[ct][r] *= corr; }
            }
            float t = fminf(fminf(m_r[0], m_r[1]), fminf(m_r[2], m_r[3]));
            t = fminf(t, __shfl_xor(t, 16, 64));
            t = fminf(t, __shfl_xor(t, 32, 64));
            mw = t;
        }

#pragma unroll
        for (int ct = 0; ct < 4; ++ct)
#pragma unroll
            for (int r = 0; r < 4; ++r) {
                float p = exp2f(S[ct][r] - m_r[r]);
                l_l[r] += p;
                Pw[(quad * 4 + r) * 72 + ct * 16 + l15] = f16_bits(p);
            }

        half8 pf0 = ldh(Pw + l15 * 72 + 0  + quad * 8);
        half8 pf1 = ldh(Pw + l15 * 72 + 32 + quad * 8);

#pragma unroll
        for (int g = 0; g < VCW; g += G) {
            __syncthreads();
#pragma unroll
            for (int s = 0; s < 4; ++s) {
                const int h = s / G, j = s % G;
                stage64_async(Vth, (long)b * C + (h * VCW + g + j) * 64, N, kt * 64,
                              smem + s * 4096, tid);
            }
            __syncthreads();
#pragma unroll
            for (int ks = 0; ks < 2; ++ks) {
                half8 pf = ks ? pf1 : pf0;
#pragma unroll
                for (int j = 0; j < G; ++j)
#pragma unroll
                    for (int ct = 0; ct < 4; ++ct) {
                        half8 vh = ldsw(smem + (ch2 * G + j) * 4096,
                                        ct * 16 + l15, ks * 32 + quad * 8);
                        half8 uh = vh * vh;
                        const int ci = (g + j) * 4 + ct;
                        Mac[ci] = MFMAH(pf, vh, Mac[ci]);
                        Sac[ci] = MFMAH(pf, uh, Sac[ci]);
                    }
            }
        }
    }

#pragma unroll
    for (int off = 1; off <= 8; off <<= 1)
#pragma unroll
        for (int r = 0; r < 4; ++r) l_l[r] += __shfl_xor(l_l[r], off, 64);

    if (ch2 == 0 && l15 == 0) {
#pragma unroll
        for (int r = 0; r < 4; ++r) {
            Pmo[po * 16 + quad * 4 + r] = m_r[r];
            Plo[po * 16 + quad * 4 + r] = l_l[r];
        }
    }
    const int chb = ch2 * (C / CSPLIT);
#pragma unroll
    for (int ct = 0; ct < CTCW; ++ct)
#pragma unroll
        for (int r = 0; r < 4; ++r) {
            long idx = (po * 16 + quad * 4 + r) * C + chb + ct * 16 + l15;
            PMo[idx] = Mac[ct][r];
            PSo[idx] = Sac[ct][r];
        }
}

__global__ void __launch_bounds__(256, 2) flash34(
    const ushort_t* __restrict__ Qh3, const ushort_t* __restrict__ Kh3,
    const ushort_t* __restrict__ Vth3,
    float* __restrict__ Pm3, float* __restrict__ Pl3,
    float* __restrict__ PM3, float* __restrict__ PS3,
    const ushort_t* __restrict__ Qh4, const ushort_t* __restrict__ Kh4,
    const ushort_t* __restrict__ Vth4,
    float* __restrict__ Pm4, float* __restrict__ Pl4,
    float* __restrict__ PM4, float* __restrict__ PS4)
{
    __shared__ __align__(16) ushort_t smem[35328];
    if ((int)blockIdx.x < 512)
        flash_body<960, 512, 1024, 2, false, 4, 5, 5>(
            Qh3, Kh3, Vth3, Pm3, Pl3, PM3, PS3, smem, (int)blockIdx.x);
    else
        flash_body<1472, 512, 256, 4, false, 2, 6, 6>(
            Qh4, Kh4, Vth4, Pm4, Pl4, PM4, PS4, smem, (int)blockIdx.x - 512);
}

// ---------------------------------------------------------------------------
// Combine body (merge SPLIT partials, inline content stats, fused MSE).
// ---------------------------------------------------------------------------
template<int C, int SPLIT>
__device__ __forceinline__ void combine_body(
    const float* __restrict__ Pm, const float* __restrict__ Pl,
    const float* __restrict__ PM, const float* __restrict__ PS,
    const float* __restrict__ CT, const float* __restrict__ CS,
    const float* __restrict__ csum, const float* __restrict__ csq,
    float invN, float* __restrict__ loss, int N, int pi, float* shm)
{
    constexpr int CL4 = C / 4;
    float (*wS)[16] = (float(*)[16])shm;
    float* invL = shm + SPLIT * 16;
    float* red  = invL + 16;
    const int nb = N / 16;
    const int b  = pi / nb;
    const long g0 = (long)b * N + (long)(pi % nb) * 16;
    const int tid = threadIdx.x;

    if (tid < 16) {
        float m = -1e30f;
#pragma unroll
        for (int s = 0; s < SPLIT; ++s)
            m = fmaxf(m, Pm[((long)pi * SPLIT + s) * 16 + tid]);
        float L = 0.f;
#pragma unroll
        for (int s = 0; s < SPLIT; ++s) {
            float e = exp2f(Pm[((long)pi * SPLIT + s) * 16 + tid] - m);
            wS[s][tid] = e;
            L = fmaf(e, Pl[((long)pi * SPLIT + s) * 16 + tid], L);
        }
        invL[tid] = 1.f / L;
    }
    __syncthreads();

    float acc = 0.f;
    for (int v = tid; v < 4 * C; v += 256) {
        const int r  = v / CL4;
        const int c0 = (v - r * CL4) * 4;
        const long q0 = (((long)pi * SPLIT) * 16 + r) * C + c0;
        float4 Ms = {0.f, 0.f, 0.f, 0.f}, Ss = {0.f, 0.f, 0.f, 0.f};
#pragma unroll
        for (int s = 0; s < SPLIT; ++s) {
            const float ws_ = wS[s][r];
            const float4 pm = *(const float4*)&PM[q0 + (long)s * 16 * C];
            const float4 ps = *(const float4*)&PS[q0 + (long)s * 16 * C];
            Ms.x = fmaf(ws_, pm.x, Ms.x); Ms.y = fmaf(ws_, pm.y, Ms.y);
            Ms.z = fmaf(ws_, pm.z, Ms.z); Ms.w = fmaf(ws_, pm.w, Ms.w);
            Ss.x = fmaf(ws_, ps.x, Ss.x); Ss.y = fmaf(ws_, ps.y, Ss.y);
            Ss.z = fmaf(ws_, ps.z, Ss.z); Ss.w = fmaf(ws_, ps.w, Ss.w);
        }
        const float iL = invL[r];
        const float4 ctv = *(const float4*)&CT[(g0 + r) * C + c0];
        const float4 csv = *(const float4*)&CS[(g0 + r) * C + c0];
        const float4 cs4 = *(const float4*)&csum[b * C + c0];
        const float4 cq4 = *(const float4*)&csq[b * C + c0];
#pragma unroll
        for (int e = 0; e < 4; ++e) {
            const float Msx = (&Ms.x)[e] * iL;
            const float S2  = (&Ss.x)[e] * iL - Msx * Msx;
            const float Sx  = sqrtf(fmaxf(S2, EPS_VAR));
            const float cm  = (&cs4.x)[e] * invN;
            const float cr  = rsqrtf((&cq4.x)[e] * invN - cm * cm + EPS_NORM);
            const float nc  = ((&ctv.x)[e] - cm) * cr;
            const float d   = (&csv.x)[e] - (Sx * nc + Msx);
            acc = fmaf(d, d, acc);
        }
    }
#pragma unroll
    for (int off = 1; off <= 32; off <<= 1) acc += __shfl_xor(acc, off, 64);
    if ((tid & 63) == 0) red[tid >> 6] = acc;
    __syncthreads();
    if (tid == 0) atomicAdd(loss, red[0] + red[1] + red[2] + red[3]);
}

// ---------------------------------------------------------------------------
// Mega-kernel parameter block
// ---------------------------------------------------------------------------
struct MegaP {
    StatJobs4 SJ; int statBlocks;
    const float *cc2, *sc2, *s2v;
    const float *q2m, *q2r, *k2m, *k2r;
    ushort_t *qh2, *kh2, *vh2;
    float *Pm, *Pl, *PM, *PS;
    const float *c2, *cs2, *c2m, *c2r;
    float* lossp;
    const float *cc3, *sc3, *s3v, *q3m, *q3r, *k3m, *k3r;
    ushort_t *qh3, *kh3, *vh3;
    const float *cc4, *sc4, *s4v, *q4m, *q4r, *k4m, *k4r;
    ushort_t *qh4, *kh4, *vh4;
    float *Pm4, *Pl4, *PM4, *PS4;
    const float *c3, *cs3, *c3m, *c3r, *c4, *cs4, *c4m, *c4r;
    float* out;
    float s0, s1, s2;
};

__global__ void __launch_bounds__(256, 2) mega(MegaP P)
{
    __shared__ __align__(16) ushort_t smem[37376];
    cg::grid_group grid = cg::this_grid();
    const int nb  = (int)gridDim.x;           // 512
    const int bid = (int)blockIdx.x;

    // ---- P1: stats ----
    for (int v = bid; v < P.statBlocks; v += nb) stat_body(P.SJ, v);
    __threadfence();
    grid.sync();

    // ---- P2: prep scale 2 (8192 norm + 1024 vtile) ----
    for (int v = bid; v < 9216; v += nb) {
        if (v < 8192)
            norm_quad(v, P.cc2, P.q2m, P.q2r, P.sc2, P.k2m, P.k2r,
                      P.qh2, P.kh2, 4096, 448, 1.0f / 4096.0f);
        else
            vtile(v - 8192, P.s2v, P.vh2, 4096, 256, smem);
        __syncthreads();
    }
    __threadfence();
    grid.sync();

    // ---- P3: flash scale 2 (512 blocks, direct) ----
    flash2_body(P.qh2, P.kh2, P.vh2, P.Pm, P.Pl, P.PM, P.PS, smem, bid);
    __threadfence();
    grid.sync();

    // ---- P4: combine2 (1024) || prep3 (2048+512) || prep4 (512+128) ----
    for (int v = bid; v < 4224; v += nb) {
        if (v < 1024)
            combine_body<256, 2>(P.Pm, P.Pl, P.PM, P.PS, P.c2, P.cs2, P.c2m, P.c2r,
                                 1.0f / 4096.0f, &P.lossp[0], 4096, v, (float*)smem);
        else if (v < 3072)
            norm_quad(v - 1024, P.cc3, P.q3m, P.q3r, P.sc3, P.k3m, P.k3r,
                      P.qh3, P.kh3, 1024, 960, 1.0f / 1024.0f);
        else if (v < 3584)
            vtile(v - 3072, P.s3v, P.vh3, 1024, 512, smem);
        else if (v < 4096)
            norm_quad(v - 3584, P.cc4, P.q4m, P.q4r, P.sc4, P.k4m, P.k4r,
                      P.qh4, P.kh4, 256, 1472, 1.0f / 256.0f);
        else
            vtile(v - 4096, P.s4v, P.vh4, 256, 512, smem);
        __syncthreads();
    }
    __threadfence();
    grid.sync();

    // ---- P5: flash scales 3+4 (640 virtual over 512 real) ----
    for (int v = bid; v < 640; v += nb) {
        if (v < 512)
            flash_body<960, 512, 1024, 2, false, 4, 5, 5>(
                P.qh3, P.kh3, P.vh3, P.Pm, P.Pl, P.PM, P.PS, smem, v);
        else
            flash_body<1472, 512, 256, 4, false, 2, 6, 6>(
                P.qh4, P.kh4, P.vh4, P.Pm4, P.Pl4, P.PM4, P.PS4, smem, v - 512);
        __syncthreads();
    }
    __threadfence();
    grid.sync();

    // ---- P6: combine3 (256) || combine4 (64) + final fold ----
    for (int v = bid; v < 320; v += nb) {
        if (v < 256)
            combine_body<512, 4>(P.Pm, P.Pl, P.PM, P.PS, P.c3, P.cs3, P.c3m, P.c3r,
                                 1.0f / 1024.0f, &P.lossp[1], 1024, v, (float*)smem);
        else
            combine_body<512, 2>(P.Pm4, P.Pl4, P.PM4, P.PS4, P.c4, P.cs4, P.c4m, P.c4r,
                                 1.0f / 256.0f, &P.lossp[2], 256, v - 256, (float*)smem);
        __threadfence();
        if (threadIdx.x == 0) {
            unsigned old = atomicAdd((unsigned*)&P.lossp[3], 1u);
            if (old == 319u) {
                float l0 = atomicAdd(&P.lossp[0], 0.0f);
                float l1 = atomicAdd(&P.lossp[1], 0.0f);
                float l2 = atomicAdd(&P.lossp[2], 0.0f);
                P.out[0] = l0 * P.s0 + l1 * P.s1 + l2 * P.s2;
            }
        }
        __syncthreads();
    }
}

// ---------------------------------------------------------------------------
// Standalone kernels for the non-cooperative fallback path (round-7 proven).
// ---------------------------------------------------------------------------
__global__ void __launch_bounds__(256) prep2(
    const float* __restrict__ qx, const float* __restrict__ qs, const float* __restrict__ qq,
    const float* __restrict__ kx, const float* __restrict__ ks, const float* __restrict__ kq,
    ushort_t* __restrict__ qh, ushort_t* __restrict__ kh,
    const float* __restrict__ vx, ushort_t* __restrict__ vt)
{
    __shared__ __align__(16) ushort_t lbuf[4608];
    int bx = blockIdx.x;
    if (bx < 8192) norm_quad(bx, qx, qs, qq, kx, ks, kq, qh, kh, 4096, 448, 1.0f / 4096.0f);
    else           vtile(bx - 8192, vx, vt, 4096, 256, lbuf);
}

struct MidP {
    const float *Pm, *Pl, *PM, *PS, *CT, *CS, *csum, *csq;
    float* loss;
    const float *q3x, *q3s, *q3q, *k3x, *k3s, *k3q, *v3x;
    ushort_t *qh3, *kh3, *vt3;
    const float *q4x, *q4s, *q4q, *k4x, *k4s, *k4q, *v4x;
    ushort_t *qh4, *kh4, *vt4;
};
__global__ void __launch_bounds__(256) mid_fused(MidP P)
{
    __shared__ __align__(16) ushort_t lbuf[4608];
    int bx = blockIdx.x;
    if (bx < 1024) {
        combine_body<256, 2>(P.Pm, P.Pl, P.PM, P.PS, P.CT, P.CS, P.csum, P.csq,
                             1.0f / 4096.0f, P.loss, 4096, bx, (float*)lbuf);
    } else if (bx < 3072) {
        norm_quad(bx - 1024, P.q3x, P.q3s, P.q3q, P.k3x, P.k3s, P.k3q,
                  P.qh3, P.kh3, 1024, 960, 1.0f / 1024.0f);
    } else if (bx < 3584) {
        vtile(bx - 3072, P.v3x, P.vt3, 1024, 512, lbuf);
    } else if (bx < 4096) {
        norm_quad(bx - 3584, P.q4x, P.q4s, P.q4q, P.k4x, P.k4s, P.k4q,
                  P.qh4, P.kh4, 256, 1472, 1.0f / 256.0f);
    } else {
        vtile(bx - 4096, P.v4x, P.vt4, 256, 512, lbuf);
    }
}

struct C34P {
    const float *Pm3, *Pl3, *PM3, *PS3, *CT3, *CS3, *c3s, *c3q;
    const float *Pm4, *Pl4, *PM4, *PS4, *CT4, *CS4, *c4s, *c4q;
    float* lossp;
    float* out;
    float s0, s1, s2;
};
__global__ void __launch_bounds__(256) combine34_final(C34P P)
{
    __shared__ float shm[4 * 16 + 20];
    int bx = blockIdx.x;
    if (bx < 256)
        combine_body<512, 4>(P.Pm3, P.Pl3, P.PM3, P.PS3, P.CT3, P.CS3, P.c3s, P.c3q,
                             1.0f / 1024.0f, &P.lossp[1], 1024, bx, shm);
    else
        combine_body<512, 2>(P.Pm4, P.Pl4, P.PM4, P.PS4, P.CT4, P.CS4, P.c4s, P.c4q,
                             1.0f / 256.0f, &P.lossp[2], 256, bx - 256, shm);
    __threadfence();
    if (threadIdx.x == 0) {
        unsigned old = atomicAdd((unsigned*)&P.lossp[3], 1u);
        if (old == 319u) {
            float l0 = atomicAdd(&P.lossp[0], 0.0f);
            float l1 = atomicAdd(&P.lossp[1], 0.0f);
            float l2 = atomicAdd(&P.lossp[2], 0.0f);
            P.out[0] = l0 * P.s0 + l1 * P.s1 + l2 * P.s2;
        }
    }
}

// ---------------------------------------------------------------------------
// Fallback scalar flash kernel (only if ws_size too small)
// ---------------------------------------------------------------------------
template<int CCL, int CL, int NQ>
__global__ void __launch_bounds__(256) flash_aat(
    const float* __restrict__ Q, const float* __restrict__ K, const float* __restrict__ V,
    const float* __restrict__ CT, const float* __restrict__ CS,
    const float* __restrict__ qmean, const float* __restrict__ qrstd,
    const float* __restrict__ kmean, const float* __restrict__ krstd,
    const float* __restrict__ cmean, const float* __restrict__ crstd,
    float* __restrict__ loss, int N)
{
    constexpr int CC   = CCL * 64;
    constexpr int C    = CL * 64;
    constexpr int ROWS = 4 * NQ;
    const int lane = threadIdx.x & 63;
    const int wave = threadIdx.x >> 6;
    const int rowBlocks = N / ROWS;
    const int b  = blockIdx.x / rowBlocks;
    const int rb = blockIdx.x % rowBlocks;
    const int i0 = rb * ROWS + wave * NQ;

    float kmu[CCL], krs[CCL];
#pragma unroll
    for (int t = 0; t < CCL; ++t) {
        int ch = lane + 64 * t;
        kmu[t] = kmean[b * CC + ch];
        krs[t] = krstd[b * CC + ch];
    }
    float q[NQ][CCL];
#pragma unroll
    for (int qi = 0; qi < NQ; ++qi) {
        long base = (long)(b * N + i0 + qi) * CC;
#pragma unroll
        for (int t = 0; t < CCL; ++t) {
            int ch = lane + 64 * t;
            q[qi][t] = (Q[base + ch] - qmean[b * CC + ch]) * qrstd[b * CC + ch];
        }
    }
    float mval[NQ], lsum[NQ];
    float Macc[NQ][CL], Sacc[NQ][CL];
#pragma unroll
    for (int qi = 0; qi < NQ; ++qi) {
        mval[qi] = -1e30f; lsum[qi] = 0.f;
#pragma unroll
        for (int t = 0; t < CL; ++t) { Macc[qi][t] = 0.f; Sacc[qi][t] = 0.f; }
    }
    for (int j = 0; j < N; ++j) {
        long kb = (long)(b * N + j) * CC;
        float dot[NQ];
#pragma unroll
        for (int qi = 0; qi < NQ; ++qi) dot[qi] = 0.f;
#pragma unroll
        for (int t = 0; t < CCL; ++t) {
            float kv = (K[kb + lane + 64 * t] - kmu[t]) * krs[t];
#pragma unroll
            for (int qi = 0; qi < NQ; ++qi) dot[qi] = fmaf(q[qi][t], kv, dot[qi]);
        }
#pragma unroll
        for (int off = 32; off > 0; off >>= 1)
#pragma unroll
            for (int qi = 0; qi < NQ; ++qi) dot[qi] += __shfl_xor(dot[qi], off, 64);
        long vb = (long)(b * N + j) * C;
        float vv[CL];
#pragma unroll
        for (int t = 0; t < CL; ++t) vv[t] = V[vb + lane + 64 * t];
#pragma unroll
        for (int qi = 0; qi < NQ; ++qi) {
            float s = dot[qi];
            float p;
            if (s > mval[qi]) {
                float cr2 = __expf(mval[qi] - s);
                lsum[qi] *= cr2;
#pragma unroll
                for (int t = 0; t < CL; ++t) { Macc[qi][t] *= cr2; Sacc[qi][t] *= cr2; }
                mval[qi] = s; p = 1.f;
            } else p = __expf(s - mval[qi]);
            lsum[qi] += p;
#pragma unroll
            for (int t = 0; t < CL; ++t) {
                float pv = p * vv[t];
                Macc[qi][t] += pv;
                Sacc[qi][t] = fmaf(pv, vv[t], Sacc[qi][t]);
            }
        }
    }
    float acc = 0.f;
#pragma unroll
    for (int qi = 0; qi < NQ; ++qi) {
        float inv_l = 1.f / lsum[qi];
        long base = (long)(b * N + i0 + qi) * C;
#pragma unroll
        for (int t = 0; t < CL; ++t) {
            int ch = lane + 64 * t;
            float M  = Macc[qi][t] * inv_l;
            float S2 = Sacc[qi][t] * inv_l - M * M;
            float S  = sqrtf(fmaxf(S2, EPS_VAR));
            float nc = (CT[base + ch] - cmean[b * C + ch]) * crstd[b * C + ch];
            float d  = CS[base + ch] - (S * nc + M);
            acc = fmaf(d, d, acc);
        }
    }
#pragma unroll
    for (int off = 32; off > 0; off >>= 1) acc += __shfl_xor(acc, off, 64);
    if (lane == 0) atomicAdd(loss, acc);
}

__global__ void combine_loss(const float* __restrict__ lp, float* __restrict__ out,
                             float s0, float s1, float s2)
{
    out[0] = lp[0] * s0 + lp[1] * s1 + lp[2] * s2;
}

// ---------------------------------------------------------------------------
extern "C" void kernel_launch(void* const* d_in, const int* in_sizes, int n_in,
                              void* d_out, int out_size, void* d_ws, size_t ws_size,
                              hipStream_t stream)
{
    const float* cs2 = (const float*)d_in[0];
    const float* c2  = (const float*)d_in[1];
    const float* s2v = (const float*)d_in[2];
    const float* cc2 = (const float*)d_in[3];
    const float* sc2 = (const float*)d_in[4];
    const float* cs3 = (const float*)d_in[5];
    const float* c3  = (const float*)d_in[6];
    const float* s3v = (const float*)d_in[7];
    const float* cc3 = (const float*)d_in[8];
    const float* sc3 = (const float*)d_in[9];
    const float* cs4 = (const float*)d_in[10];
    const float* c4  = (const float*)d_in[11];
    const float* s4v = (const float*)d_in[12];
    const float* cc4 = (const float*)d_in[13];
    const float* sc4 = (const float*)d_in[14];

    const int B = 4;
    float* ws = (float*)d_ws;
    size_t fo = 0;
    auto allocF = [&](size_t n) { float* p = ws + fo; fo += n; return p; };

    float* lossp = allocF(4);
    float* c2m = allocF(B * 256);  float* c2r = allocF(B * 256);
    float* q2m = allocF(B * 448);  float* q2r = allocF(B * 448);
    float* k2m = allocF(B * 448);  float* k2r = allocF(B * 448);
    float* c3m = allocF(B * 512);  float* c3r = allocF(B * 512);
    float* q3m = allocF(B * 960);  float* q3r = allocF(B * 960);
    float* k3m = allocF(B * 960);  float* k3r = allocF(B * 960);
    float* c4m = allocF(B * 512);  float* c4r = allocF(B * 512);
    float* q4m = allocF(B * 1472); float* q4r = allocF(B * 1472);
    float* k4m = allocF(B * 1472); float* k4r = allocF(B * 1472);
    size_t zeroBytes = fo * sizeof(float);

    float* Pm = allocF(32768);
    float* Pl = allocF(32768);
    float* PM = allocF(8388608);
    float* PS = allocF(8388608);

    size_t arenaOff = ((fo * 4 + 15) & ~(size_t)15) / 2;
    ushort_t* arena = (ushort_t*)d_ws + arenaOff;
    const size_t arenaShorts = 18874400;
    size_t need = arenaOff * 2 + arenaShorts * 2;
    const bool fast = (ws_size >= need);

    hipMemsetAsync(d_ws, 0, zeroBytes, stream);

    // ---- build stat job table (vectorized) ----
    StatJobs4 SJ;
    int statBlocks = 0;
    {
        const float* xs[9] = {c2, cc2, sc2, c3, cc3, sc3, c4, cc4, sc4};
        float* sms[9] = {c2m, q2m, k2m, c3m, q3m, k3m, c4m, q4m, k4m};
        float* sqs[9] = {c2r, q2r, k2r, c3r, q3r, k3r, c4r, q4r, k4r};
        const int Ns[9]  = {4096, 4096, 4096, 1024, 1024, 1024, 256, 256, 256};
        const int Cns[9] = {256, 448, 448, 512, 960, 960, 512, 1472, 1472};
        for (int j = 0; j < 9; ++j) {
            int cG = (Cns[j] + 255) / 256;
            int nG = (Ns[j] + 127) / 128;
            SJ.x[j] = xs[j]; SJ.sm[j] = sms[j]; SJ.sq[j] = sqs[j];
            SJ.N[j] = Ns[j]; SJ.Cn[j] = Cns[j]; SJ.cG[j] = cG; SJ.nG[j] = nG;
            SJ.base[j] = statBlocks;
            statBlocks += B * cG * nG;
        }
    }

    if (fast) {
        ushort_t* qh2 = arena;
        ushort_t* kh2 = qh2 + (size_t)B * 4096 * 448;
        ushort_t* vh2 = kh2 + (size_t)B * 4096 * 448;
        ushort_t* qh3 = arena;
        ushort_t* kh3 = qh3 + (size_t)B * 1024 * 960;
        ushort_t* vh3 = kh3 + (size_t)B * 1024 * 960;
        ushort_t* qh4 = vh3 + (size_t)B * 1024 * 512;
        ushort_t* kh4 = qh4 + (size_t)B * 256 * 1472;
        ushort_t* vh4 = kh4 + (size_t)B * 256 * 1472;
        size_t o34 = (size_t)B * 1024 * 960 * 2 + (size_t)B * 1024 * 512
                   + (size_t)B * 256 * 1472 * 2 + (size_t)B * 256 * 512;
        float* PM4 = (float*)(arena + o34);
        float* PS4 = PM4 + 1048576;
        float* Pm4 = Pm + 16384;
        float* Pl4 = Pl + 16384;

        // ---- try single cooperative mega-kernel ----
        MegaP MP;
        MP.SJ = SJ; MP.statBlocks = statBlocks;
        MP.cc2 = cc2; MP.sc2 = sc2; MP.s2v = s2v;
        MP.q2m = q2m; MP.q2r = q2r; MP.k2m = k2m; MP.k2r = k2r;
        MP.qh2 = qh2; MP.kh2 = kh2; MP.vh2 = vh2;
        MP.Pm = Pm; MP.Pl = Pl; MP.PM = PM; MP.PS = PS;
        MP.c2 = c2; MP.cs2 = cs2; MP.c2m = c2m; MP.c2r = c2r;
        MP.lossp = lossp;
        MP.cc3 = cc3; MP.sc3 = sc3; MP.s3v = s3v;
        MP.q3m = q3m; MP.q3r = q3r; MP.k3m = k3m; MP.k3r = k3r;
        MP.qh3 = qh3; MP.kh3 = kh3; MP.vh3 = vh3;
        MP.cc4 = cc4; MP.sc4 = sc4; MP.s4v = s4v;
        MP.q4m = q4m; MP.q4r = q4r; MP.k4m = k4m; MP.k4r = k4r;
        MP.qh4 = qh4; MP.kh4 = kh4; MP.vh4 = vh4;
        MP.Pm4 = Pm4; MP.Pl4 = Pl4; MP.PM4 = PM4; MP.PS4 = PS4;
        MP.c3 = c3; MP.cs3 = cs3; MP.c3m = c3m; MP.c3r = c3r;
        MP.c4 = c4; MP.cs4 = cs4; MP.c4m = c4m; MP.c4r = c4r;
        MP.out = (float*)d_out;
        MP.s0 = 1.0f / (4.0f * 4096.0f * 256.0f);
        MP.s1 = 1.0f / (4.0f * 1024.0f * 512.0f);
        MP.s2 = 1.0f / (4.0f * 256.0f * 512.0f);

        void* args[] = { (void*)&MP };
        hipError_t er = hipLaunchCooperativeKernel(
            reinterpret_cast<void*>(mega), dim3(512), dim3(256), args, 0, stream);

        if (er != hipSuccess) {
            // ---- proven 7-dispatch fallback (round 7) ----
            hipLaunchKernelGGL(stat_partial_all, dim3(statBlocks), dim3(256), 0, stream, SJ);
            hipLaunchKernelGGL(prep2, dim3(8192 + 1024), dim3(256), 0, stream,
                               cc2, q2m, q2r, sc2, k2m, k2r, qh2, kh2, s2v, vh2);
            hipLaunchKernelGGL(flash_pipe, dim3(512), dim3(256), 0, stream,
                               qh2, kh2, vh2, Pm, Pl, PM, PS);
            {
                MidP MDP;
                MDP.Pm = Pm; MDP.Pl = Pl; MDP.PM = PM; MDP.PS = PS;
                MDP.CT = c2; MDP.CS = cs2; MDP.csum = c2m; MDP.csq = c2r;
                MDP.loss = &lossp[0];
                MDP.q3x = cc3; MDP.q3s = q3m; MDP.q3q = q3r;
                MDP.k3x = sc3; MDP.k3s = k3m; MDP.k3q = k3r; MDP.v3x = s3v;
                MDP.qh3 = qh3; MDP.kh3 = kh3; MDP.vt3 = vh3;
                MDP.q4x = cc4; MDP.q4s = q4m; MDP.q4q = q4r;
                MDP.k4x = sc4; MDP.k4s = k4m; MDP.k4q = k4r; MDP.v4x = s4v;
                MDP.qh4 = qh4; MDP.kh4 = kh4; MDP.vt4 = vh4;
                hipLaunchKernelGGL(mid_fused, dim3(4224), dim3(256), 0, stream, MDP);
            }
            hipLaunchKernelGGL(flash34, dim3(512 + 128), dim3(256), 0, stream,
                               qh3, kh3, vh3, Pm, Pl, PM, PS,
                               qh4, kh4, vh4, Pm4, Pl4, PM4, PS4);
            {
                C34P CP;
                CP.Pm3 = Pm; CP.Pl3 = Pl; CP.PM3 = PM; CP.PS3 = PS;
                CP.CT3 = c3; CP.CS3 = cs3; CP.c3s = c3m; CP.c3q = c3r;
                CP.Pm4 = Pm4; CP.Pl4 = Pl4; CP.PM4 = PM4; CP.PS4 = PS4;
                CP.CT4 = c4; CP.CS4 = cs4; CP.c4s = c4m; CP.c4q = c4r;
                CP.lossp = lossp; CP.out = (float*)d_out;
                CP.s0 = 1.0f / (4.0f * 4096.0f * 256.0f);
                CP.s1 = 1.0f / (4.0f * 1024.0f * 512.0f);
                CP.s2 = 1.0f / (4.0f * 256.0f * 512.0f);
                hipLaunchKernelGGL(combine34_final, dim3(256 + 64), dim3(256), 0, stream, CP);
            }
        }
    } else {
        hipLaunchKernelGGL(stat_partial_all, dim3(statBlocks), dim3(256), 0, stream, SJ);
        {
            FinJobs FJ;
            float* sms[9] = {c2m, q2m, k2m, c3m, q3m, k3m, c4m, q4m, k4m};
            float* sqs[9] = {c2r, q2r, k2r, c3r, q3r, k3r, c4r, q4r, k4r};
            const int Ns[9]  = {4096, 4096, 4096, 1024, 1024, 1024, 256, 256, 256};
            const int Cns[9] = {256, 448, 448, 512, 960, 960, 512, 1472, 1472};
            int fb = 0;
            for (int j = 0; j < 9; ++j) {
                FJ.sm[j] = sms[j]; FJ.sq[j] = sqs[j]; FJ.base[j] = fb;
                FJ.invN[j] = 1.0f / (float)Ns[j];
                fb += B * Cns[j];
            }
            FJ.total = fb;
            hipLaunchKernelGGL(stat_finalize_all, dim3((fb + 255) / 256), dim3(256), 0, stream, FJ);
        }
        hipLaunchKernelGGL((flash_aat<7, 4, 4>), dim3(B * 4096 / 16), dim3(256), 0, stream,
                           cc2, sc2, s2v, c2, cs2, q2m, q2r, k2m, k2r, c2m, c2r, &lossp[0], 4096);
        hipLaunchKernelGGL((flash_aat<15, 8, 2>), dim3(B * 1024 / 8), dim3(256), 0, stream,
                           cc3, sc3, s3v, c3, cs3, q3m, q3r, k3m, k3r, c3m, c3r, &lossp[1], 1024);
        hipLaunchKernelGGL((flash_aat<23, 8, 2>), dim3(B * 256 / 8), dim3(256), 0, stream,
                           cc4, sc4, s4v, c4, cs4, q4m, q4r, k4m, k4r, c4m, c4r, &lossp[2], 256);
        hipLaunchKernelGGL(combine_loss, dim3(1), dim3(1), 0, stream,
                           lossp, (float*)d_out,
                           1.0f / (4.0f * 4096.0f * 256.0f),
                           1.0f / (4.0f * 1024.0f * 512.0f),
                           1.0f / (4.0f * 256.0f * 512.0f));
    }
}

// Round 9
// 649.121 us; speedup vs baseline: 2.1096x; 2.1096x over previous
//
#include <hip/hip_runtime.h>
#include <math.h>

#define EPS_NORM 1e-5f
#define EPS_VAR  1e-9f
#define LOG2E    1.4426950408889634f

typedef unsigned short ushort_t;
typedef __attribute__((ext_vector_type(4))) float f32x4;
typedef _Float16 half8 __attribute__((ext_vector_type(8)));

#define MFMAH(a, b, c) __builtin_amdgcn_mfma_f32_16x16x32_f16((a), (b), (c), 0, 0, 0)

#define GLD16(gp, lp) __builtin_amdgcn_global_load_lds(                          \
    (const __attribute__((address_space(1))) unsigned int*)(gp),                 \
    (__attribute__((address_space(3))) unsigned int*)(lp), 16, 0, 0)

// ---------------------------------------------------------------------------
// fp16 helpers
// ---------------------------------------------------------------------------
__device__ inline ushort_t f16_bits(float x) {
    _Float16 h = (_Float16)x;
    ushort_t u;
    __builtin_memcpy(&u, &h, 2);
    return u;
}
__device__ inline half8 ldh(const ushort_t* p) {
    half8 h;
    __builtin_memcpy(&h, p, 16);
    return h;
}
__device__ inline uint4 pack8(const ushort_t* s) {
    uint4 r;
    r.x = (unsigned)s[0] | ((unsigned)s[1] << 16);
    r.y = (unsigned)s[2] | ((unsigned)s[3] << 16);
    r.z = (unsigned)s[4] | ((unsigned)s[5] << 16);
    r.w = (unsigned)s[6] | ((unsigned)s[7] << 16);
    return r;
}

// ---------------------------------------------------------------------------
// Stats: float4-vectorized (4 channels x 32 rows per thread, 16B/lane)
// ---------------------------------------------------------------------------
struct StatJobs4 {
    const float* x[9];
    float* sm[9];
    float* sq[9];
    int N[9], Cn[9], cG[9], nG[9], base[9];   // cG = ceil(Cn/256)
};
__global__ void __launch_bounds__(256) stat_partial_all(StatJobs4 J)
{
    int bx = (int)blockIdx.x;
    int j = 0;
#pragma unroll
    for (int k = 1; k < 9; ++k) if (bx >= J.base[k]) j = k;
    bx -= J.base[j];
    const int N = J.N[j], Cn = J.Cn[j], cG = J.cG[j], nG = J.nG[j];
    const int b   = bx / (cG * nG);
    const int r   = bx % (cG * nG);
    const int cgi = r / nG;
    const int ng  = r % nG;
    const int lane = threadIdx.x & 63, wv = threadIdx.x >> 6;
    const int c4 = cgi * 64 + lane;            // float4 index
    if (c4 * 4 >= Cn) return;
    const int n0 = ng * 128 + wv * 32;
    if (n0 >= N) return;
    const int n1 = min(n0 + 32, N);
    const int c4s = Cn >> 2;
    const float4* p = (const float4*)(J.x[j] + (long)(b * N) * Cn) + (long)n0 * c4s + c4;
    float4 s  = {0.f, 0.f, 0.f, 0.f};
    float4 ss = {0.f, 0.f, 0.f, 0.f};
    for (int n = n0; n < n1; ++n) {
        float4 v = *p;
        p += c4s;
        s.x += v.x; s.y += v.y; s.z += v.z; s.w += v.w;
        ss.x = fmaf(v.x, v.x, ss.x); ss.y = fmaf(v.y, v.y, ss.y);
        ss.z = fmaf(v.z, v.z, ss.z); ss.w = fmaf(v.w, v.w, ss.w);
    }
    float* smp = J.sm[j] + b * Cn + c4 * 4;
    float* sqp = J.sq[j] + b * Cn + c4 * 4;
#pragma unroll
    for (int e = 0; e < 4; ++e) {
        atomicAdd(&smp[e], (&s.x)[e]);
        atomicAdd(&sqp[e], (&ss.x)[e]);
    }
}

// finalize kept ONLY for the scalar fallback path
struct FinJobs {
    float* sm[9];
    float* sq[9];
    int base[9];
    float invN[9];
    int total;
};
__global__ void __launch_bounds__(256) stat_finalize_all(FinJobs J)
{
    int i = blockIdx.x * 256 + threadIdx.x;
    if (i >= J.total) return;
    int j = 0;
#pragma unroll
    for (int k = 1; k < 9; ++k) if (i >= J.base[k]) j = k;
    int e = i - J.base[j];
    float m = J.sm[j][e] * J.invN[j];
    float v = J.sq[j][e] * J.invN[j] - m * m;
    J.sm[j][e] = m;
    J.sq[j][e] = rsqrtf(v + EPS_NORM);
}

// ---------------------------------------------------------------------------
// norm (inline finalize, wave-per-row, float4) and V-transpose via LDS tile.
// ---------------------------------------------------------------------------
__device__ __forceinline__ void norm_quad(
    int bx, const float* __restrict__ qx, const float* __restrict__ qs,
    const float* __restrict__ qq, const float* __restrict__ kx,
    const float* __restrict__ ks, const float* __restrict__ kq,
    ushort_t* __restrict__ qh, ushort_t* __restrict__ kh,
    int N, int Cc, float invN)
{
    const int wave = threadIdx.x >> 6, lane = threadIdx.x & 63;
    int rr = bx * 4 + wave;
    const int BN = 4 * N;
    const bool isQ = rr < BN;
    int bn = isQ ? rr : rr - BN;
    const float* x  = isQ ? qx : kx;
    const float* sm = isQ ? qs : ks;
    const float* sq = isQ ? qq : kq;
    ushort_t* out   = isQ ? qh : kh;
    const float scl = isQ ? LOG2E : 1.0f;
    int b = bn / N;
    long base = (long)bn * Cc;
    const float* smb = sm + b * Cc;
    const float* sqb = sq + b * Cc;
    for (int c8 = lane; c8 * 8 < Cc; c8 += 64) {
        int ch = c8 * 8;
        float4 a0 = *(const float4*)(x + base + ch);
        float4 a1 = *(const float4*)(x + base + ch + 4);
        float4 s0 = *(const float4*)(smb + ch);
        float4 s1 = *(const float4*)(smb + ch + 4);
        float4 t0 = *(const float4*)(sqb + ch);
        float4 t1 = *(const float4*)(sqb + ch + 4);
        ushort_t h8[8];
#pragma unroll
        for (int e = 0; e < 4; ++e) {
            float m = (&s0.x)[e] * invN;
            float r = rsqrtf((&t0.x)[e] * invN - m * m + EPS_NORM);
            h8[e] = f16_bits(((&a0.x)[e] - m) * r * scl);
        }
#pragma unroll
        for (int e = 0; e < 4; ++e) {
            float m = (&s1.x)[e] * invN;
            float r = rsqrtf((&t1.x)[e] * invN - m * m + EPS_NORM);
            h8[4 + e] = f16_bits(((&a1.x)[e] - m) * r * scl);
        }
        *(uint4*)(out + base + ch) = pack8(h8);
    }
}

__device__ __forceinline__ void vtile(
    int bid2, const float* __restrict__ vx, ushort_t* __restrict__ vt,
    int N, int C, ushort_t* tbuf)
{
    const int cT = C >> 6, nT = N >> 6;
    int b   = bid2 / (cT * nT);
    int rem = bid2 % (cT * nT);
    int ch0 = (rem / nT) << 6;
    int n0  = (rem % nT) << 6;
    const int lane = threadIdx.x & 63, wv = threadIdx.x >> 6;
    const float* vb_ = vx + (long)b * N * C + ch0 + lane;
#pragma unroll
    for (int jj = 0; jj < 2; ++jj) {
        int nl = wv * 16 + jj * 8;
        ushort_t h8[8];
#pragma unroll
        for (int i = 0; i < 8; ++i)
            h8[i] = f16_bits(vb_[(long)(n0 + nl + i) * C]);
        *(uint4*)&tbuf[lane * 72 + nl] = pack8(h8);
    }
    __syncthreads();
    {
        const int chl = threadIdx.x >> 2;
        const int nq  = (threadIdx.x & 3) * 16;
        ushort_t* op = vt + ((long)b * C + ch0 + chl) * N + n0 + nq;
        *(uint4*)op       = *(const uint4*)&tbuf[chl * 72 + nq];
        *(uint4*)(op + 8) = *(const uint4*)&tbuf[chl * 72 + nq + 8];
    }
}

// prep for scale 2 only (norm q2/k2 + V2 transpose)
__global__ void __launch_bounds__(256) prep2(
    const float* __restrict__ qx, const float* __restrict__ qs, const float* __restrict__ qq,
    const float* __restrict__ kx, const float* __restrict__ ks, const float* __restrict__ kq,
    ushort_t* __restrict__ qh, ushort_t* __restrict__ kh,
    const float* __restrict__ vx, ushort_t* __restrict__ vt)
{
    __shared__ __align__(16) ushort_t lbuf[4608];
    int bx = blockIdx.x;
    if (bx < 8192) norm_quad(bx, qx, qs, qq, kx, ks, kq, qh, kh, 4096, 448, 1.0f / 4096.0f);
    else           vtile(bx - 8192, vx, vt, 4096, 256, lbuf);
}

// ---------------------------------------------------------------------------
// Async DMA tile stagers.  LDS tiles 64 shorts/row, XOR-swizzled.
// ---------------------------------------------------------------------------
__device__ inline void stage64_async(const ushort_t* __restrict__ g, long rowBase,
                                     int gstride, int col0, ushort_t* slab, int tid)
{
    const int l  = tid & 63, w = tid >> 6;
    const int rs = l >> 3;
    const int cg = (l & 7) ^ rs;
#pragma unroll
    for (int i = 0; i < 2; ++i) {
        const int r = w * 16 + i * 8 + rs;
        const ushort_t* gp = g + (rowBase + r) * (long)gstride + col0 + (cg << 3);
        ushort_t* lp = slab + (w * 16 + i * 8) * 64 + l * 8;
        GLD16(gp, lp);
    }
}
template<int BROWS>
__device__ inline void stageQ_async(const ushort_t* __restrict__ g, long rowBase,
                                    int gstride, int col0, ushort_t* slab, int tid)
{
    if (tid < BROWS * 8) {
        const int l  = tid & 63, w = tid >> 6;
        const int rs = l >> 3;
        const int cg = (l & 7) ^ rs;
        const int r  = w * 8 + rs;
        const ushort_t* gp = g + (rowBase + r) * (long)gstride + col0 + (cg << 3);
        ushort_t* lp = slab + w * 8 * 64 + l * 8;
        GLD16(gp, lp);
    }
}
__device__ inline half8 ldsw(const ushort_t* slab, int row, int soff)
{
    const int gr = (soff >> 3) ^ (row & 7);
    return ldh(slab + row * 64 + (gr << 3));
}

// ---------------------------------------------------------------------------
// Pipelined flash for scale 2 (proven 243 us; register-bound at 2 waves/SIMD)
// ---------------------------------------------------------------------------
__global__ void __launch_bounds__(256, 2) flash_pipe(
    const ushort_t* __restrict__ Qh, const ushort_t* __restrict__ Kh,
    const ushort_t* __restrict__ Vth,
    float* __restrict__ Pmo, float* __restrict__ Plo,
    float* __restrict__ PMo, float* __restrict__ PSo)
{
    constexpr int Cc = 448, C = 256, N = 4096, SPLIT = 2;
    constexpr int NKT  = (N / 64) / SPLIT;
    constexpr long VCHO = 64L * N;
    constexpr long KADV = 64L * Cc;

    __shared__ __align__(16) ushort_t smem[4 * 8192 + 4 * 1152];
    const int tid  = threadIdx.x;
    const int lane = tid & 63;
    const int w    = tid >> 6;
    const int l15  = lane & 15;
    const int quad = lane >> 4;

    const int grp = blockIdx.x & 7;
    const int sp  = grp & 1;
    const int b   = grp >> 1;
    const int qb  = (int)(blockIdx.x >> 3);
    const int i0 = qb * 64 + w * 16;
    const long po = (long)(b * (N / 16) + qb * 4 + w) * SPLIT + sp;

    const int rs    = lane >> 3;
    const int cg    = (lane & 7) ^ rs;
    const int ldso0 = w * 1024 + lane * 8;
    const int ldso1 = ldso0 + 512;
    const int xh    = l15 & 7;
    const int lb0   = l15 * 64 + ((quad)     ^ xh) * 8;
    const int lb1   = l15 * 64 + ((4 + quad) ^ xh) * 8;
    ushort_t* const Pw  = smem + 32768 + w * 1152;
    ushort_t* const pww = Pw + quad * 288 + l15;
    const ushort_t* const pfr = Pw + l15 * 72 + quad * 8;

    const long krow0 = (long)b * N + (long)sp * NKT * 64;
    const ushort_t* kp0 = Kh + (krow0 + w * 16 + rs) * (long)Cc + (cg << 3);
    const ushort_t* kp1 = kp0 + 8 * Cc;
    const ushort_t* vp0 = Vth + ((long)b * C + w * 16 + rs) * (long)N
                              + (cg << 3) + (long)sp * NKT * 64;
    const ushort_t* vp1 = vp0 + 8 * (long)N;

#define SLOT(k) (smem + (k) * 8192)
#define STGKP(c0, c1, slot, toff) do {                                           \
    GLD16(kp0 + (toff) + (c0) * 64, SLOT(slot) + ldso0);                         \
    GLD16(kp1 + (toff) + (c0) * 64, SLOT(slot) + ldso1);                         \
    GLD16(kp0 + (toff) + (c1) * 64, SLOT(slot) + 4096 + ldso0);                  \
    GLD16(kp1 + (toff) + (c1) * 64, SLOT(slot) + 4096 + ldso1); } while (0)
#define STGK1(c0, slot, toff) do {                                               \
    GLD16(kp0 + (toff) + (c0) * 64, SLOT(slot) + ldso0);                         \
    GLD16(kp1 + (toff) + (c0) * 64, SLOT(slot) + ldso1); } while (0)
#define STGVP(j0, slot, voff) do {                                               \
    GLD16(vp0 + (voff) + (j0) * VCHO, SLOT(slot) + ldso0);                       \
    GLD16(vp1 + (voff) + (j0) * VCHO, SLOT(slot) + ldso1);                       \
    GLD16(vp0 + (voff) + ((j0) + 1) * VCHO, SLOT(slot) + 4096 + ldso0);          \
    GLD16(vp1 + (voff) + ((j0) + 1) * VCHO, SLOT(slot) + 4096 + ldso1); } while (0)

#define WAITV(NN) asm volatile("s_waitcnt vmcnt(" #NN ")" ::: "memory");         \
    __builtin_amdgcn_sched_barrier(0);                                           \
    __builtin_amdgcn_s_barrier();                                                \
    __builtin_amdgcn_s_setprio(1);
#define PH_END __builtin_amdgcn_s_setprio(0);

#define QKPAIR(slot, c0) do {                                                    \
    const ushort_t* s0_ = SLOT(slot);                                            \
    const ushort_t* s1_ = s0_ + 4096;                                            \
    _Pragma("unroll")                                                            \
    for (int ct = 0; ct < 4; ++ct) S[ct] = MFMAH(qf[2*(c0)+0], ldh(s0_ + ct*1024 + lb0), S[ct]); \
    _Pragma("unroll")                                                            \
    for (int ct = 0; ct < 4; ++ct) S[ct] = MFMAH(qf[2*(c0)+1], ldh(s0_ + ct*1024 + lb1), S[ct]); \
    _Pragma("unroll")                                                            \
    for (int ct = 0; ct < 4; ++ct) S[ct] = MFMAH(qf[2*(c0)+2], ldh(s1_ + ct*1024 + lb0), S[ct]); \
    _Pragma("unroll")                                                            \
    for (int ct = 0; ct < 4; ++ct) S[ct] = MFMAH(qf[2*(c0)+3], ldh(s1_ + ct*1024 + lb1), S[ct]); } while (0)
#define QK1(slot, c0) do {                                                       \
    const ushort_t* s0_ = SLOT(slot);                                            \
    _Pragma("unroll")                                                            \
    for (int ct = 0; ct < 4; ++ct) S[ct] = MFMAH(qf[2*(c0)+0], ldh(s0_ + ct*1024 + lb0), S[ct]); \
    _Pragma("unroll")                                                            \
    for (int ct = 0; ct < 4; ++ct) S[ct] = MFMAH(qf[2*(c0)+1], ldh(s0_ + ct*1024 + lb1), S[ct]); } while (0)
#define PVPAIR(slot, ci0) do {                                                   \
    const ushort_t* s0_ = SLOT(slot);                                            \
    const ushort_t* s1_ = s0_ + 4096;                                            \
    _Pragma("unroll")                                                            \
    for (int ct = 0; ct < 4; ++ct) {                                             \
        half8 vh = ldh(s0_ + ct*1024 + lb0); half8 uh = vh * vh;                 \
        Mac[(ci0)*4 + ct] = MFMAH(pf0, vh, Mac[(ci0)*4 + ct]);                   \
        Sac[(ci0)*4 + ct] = MFMAH(pf0, uh, Sac[(ci0)*4 + ct]); }                 \
    _Pragma("unroll")                                                            \
    for (int ct = 0; ct < 4; ++ct) {                                             \
        half8 vh = ldh(s0_ + ct*1024 + lb1); half8 uh = vh * vh;                 \
        Mac[(ci0)*4 + ct] = MFMAH(pf1, vh, Mac[(ci0)*4 + ct]);                   \
        Sac[(ci0)*4 + ct] = MFMAH(pf1, uh, Sac[(ci0)*4 + ct]); }                 \
    _Pragma("unroll")                                                            \
    for (int ct = 0; ct < 4; ++ct) {                                             \
        half8 vh = ldh(s1_ + ct*1024 + lb0); half8 uh = vh * vh;                 \
        Mac[(ci0+1)*4 + ct] = MFMAH(pf0, vh, Mac[(ci0+1)*4 + ct]);               \
        Sac[(ci0+1)*4 + ct] = MFMAH(pf0, uh, Sac[(ci0+1)*4 + ct]); }             \
    _Pragma("unroll")                                                            \
    for (int ct = 0; ct < 4; ++ct) {                                             \
        half8 vh = ldh(s1_ + ct*1024 + lb1); half8 uh = vh * vh;                 \
        Mac[(ci0+1)*4 + ct] = MFMAH(pf1, vh, Mac[(ci0+1)*4 + ct]);               \
        Sac[(ci0+1)*4 + ct] = MFMAH(pf1, uh, Sac[(ci0+1)*4 + ct]); } } while (0)
#define RESET_S do {                                                             \
    _Pragma("unroll")                                                            \
    for (int ct = 0; ct < 4; ++ct)                                               \
        _Pragma("unroll")                                                        \
        for (int r = 0; r < 4; ++r) S[ct][r] = 0.f; } while (0)

    half8 qf[14];
    {
        const ushort_t* q1 = Qh + ((long)(b * N + i0 + l15)) * Cc + quad * 8;
#pragma unroll
        for (int ks = 0; ks < 14; ++ks) qf[ks] = ldh(q1 + ks * 32);
    }
    asm volatile("s_waitcnt vmcnt(0)" ::: "memory");

    float m_r[4], l_l[4], mw = -1e30f;
    f32x4 Mac[16], Sac[16];
    f32x4 S[4];
    half8 pf0, pf1;
#pragma unroll
    for (int r = 0; r < 4; ++r) { m_r[r] = -1e30f; l_l[r] = 0.f; }
#pragma unroll
    for (int ct = 0; ct < 16; ++ct)
#pragma unroll
        for (int r = 0; r < 4; ++r) { Mac[ct][r] = 0.f; Sac[ct][r] = 0.f; }

    auto softmax_step = [&]() {
        float tmax = S[0][0];
#pragma unroll
        for (int ct = 0; ct < 4; ++ct)
#pragma unroll
            for (int r = 0; r < 4; ++r) tmax = fmaxf(tmax, S[ct][r]);
#pragma unroll
        for (int off = 1; off <= 32; off <<= 1)
            tmax = fmaxf(tmax, __shfl_xor(tmax, off, 64));

        if (tmax > mw + 14.4269504f) {
            float rm[4];
#pragma unroll
            for (int r = 0; r < 4; ++r)
                rm[r] = fmaxf(fmaxf(S[0][r], S[1][r]), fmaxf(S[2][r], S[3][r]));
#pragma unroll
            for (int off = 1; off <= 8; off <<= 1)
#pragma unroll
                for (int r = 0; r < 4; ++r)
                    rm[r] = fmaxf(rm[r], __shfl_xor(rm[r], off, 64));
#pragma unroll
            for (int r = 0; r < 4; ++r) {
                float mn = fmaxf(m_r[r], rm[r]);
                float corr = exp2f(m_r[r] - mn);
                m_r[r] = mn;
                l_l[r] *= corr;
#pragma unroll
                for (int ct = 0; ct < 16; ++ct) { Mac[ct][r] *= corr; Sac[ct][r] *= corr; }
            }
            float tt = fminf(fminf(m_r[0], m_r[1]), fminf(m_r[2], m_r[3]));
            tt = fminf(tt, __shfl_xor(tt, 16, 64));
            tt = fminf(tt, __shfl_xor(tt, 32, 64));
            mw = tt;
        }
#pragma unroll
        for (int ct = 0; ct < 4; ++ct)
#pragma unroll
            for (int r = 0; r < 4; ++r) {
                float p = exp2f(S[ct][r] - m_r[r]);
                l_l[r] += p;
                pww[r * 72 + ct * 16] = f16_bits(p);
            }
        pf0 = ldh(pfr);
        pf1 = ldh(pfr + 32);
    };

    STGKP(0, 1, 0, 0);
    STGKP(2, 3, 1, 0);

    for (int it = 0; it < NKT / 2; ++it) {
        RESET_S;
        STGKP(4, 5, 2, 0);
        WAITV(8)  QKPAIR(0, 0); PH_END;
        STGK1(6, 3, 0);
        WAITV(6)  QKPAIR(1, 2); PH_END;
        STGVP(0, 0, 0);
        WAITV(6)  QKPAIR(2, 4); PH_END;
        STGVP(2, 1, 0);
        WAITV(8)  QK1(3, 6); PH_END;
        softmax_step();
        STGKP(0, 1, 2, KADV);
        WAITV(8)  PVPAIR(0, 0); PH_END;
        STGKP(2, 3, 3, KADV);
        WAITV(8)  PVPAIR(1, 2); PH_END;

        RESET_S;
        STGKP(4, 5, 0, KADV);
        WAITV(8)  QKPAIR(2, 0); PH_END;
        STGK1(6, 1, KADV);
        WAITV(6)  QKPAIR(3, 2); PH_END;
        STGVP(0, 2, 64);
        WAITV(6)  QKPAIR(0, 4); PH_END;
        STGVP(2, 3, 64);
        WAITV(8)  QK1(1, 6); PH_END;
        softmax_step();
        const bool more = (it + 1 < NKT / 2);
        if (more) {
            kp0 += 2 * KADV; kp1 += 2 * KADV;
            STGKP(0, 1, 0, 0);
            asm volatile("s_waitcnt vmcnt(8)" ::: "memory");
        } else {
            asm volatile("s_waitcnt vmcnt(4)" ::: "memory");
        }
        __builtin_amdgcn_sched_barrier(0);
        __builtin_amdgcn_s_barrier();
        __builtin_amdgcn_s_setprio(1);
        PVPAIR(2, 0);
        PH_END;
        if (more) {
            STGKP(2, 3, 1, 0);
            asm volatile("s_waitcnt vmcnt(8)" ::: "memory");
        } else {
            asm volatile("s_waitcnt vmcnt(0)" ::: "memory");
        }
        __builtin_amdgcn_sched_barrier(0);
        __builtin_amdgcn_s_barrier();
        __builtin_amdgcn_s_setprio(1);
        PVPAIR(3, 2);
        PH_END;

        vp0 += 128; vp1 += 128;
    }
#undef SLOT
#undef STGKP
#undef STGK1
#undef STGVP
#undef WAITV
#undef PH_END
#undef QKPAIR
#undef QK1
#undef PVPAIR
#undef RESET_S

#pragma unroll
    for (int off = 1; off <= 8; off <<= 1)
#pragma unroll
        for (int r = 0; r < 4; ++r) l_l[r] += __shfl_xor(l_l[r], off, 64);

    if (l15 == 0) {
#pragma unroll
        for (int r = 0; r < 4; ++r) {
            Pmo[po * 16 + quad * 4 + r] = m_r[r];
            Plo[po * 16 + quad * 4 + r] = l_l[r];
        }
    }
#pragma unroll
    for (int ct = 0; ct < 16; ++ct)
#pragma unroll
        for (int r = 0; r < 4; ++r) {
            long idx = (po * 16 + quad * 4 + r) * C + ct * 16 + l15;
            PMo[idx] = Mac[ct][r];
            PSo[idx] = Sac[ct][r];
        }
}

// ---------------------------------------------------------------------------
// Generic flash body (scales 3/4): QK chunk-split + S-merge (round-6 proven).
// ---------------------------------------------------------------------------
template<int Cc, int C, int N, int CSPLIT, bool QREG, int SPLIT, int SLABS, int KGRP>
__device__ __forceinline__ void flash_body(
    const ushort_t* __restrict__ Qh, const ushort_t* __restrict__ Kh,
    const ushort_t* __restrict__ Vth,
    float* __restrict__ Pmo, float* __restrict__ Plo,
    float* __restrict__ PMo, float* __restrict__ PSo,
    ushort_t* smem, int bid)
{
    constexpr int KC      = Cc / 64;
    constexpr int VC      = C / 64;
    constexpr int VCW     = VC / CSPLIT;
    constexpr int CTCW    = 4 * VCW;
    constexpr int STRIPES = 4 / CSPLIT;
    constexpr int BROWS   = 16 * STRIPES;
    constexpr int QB      = N / BROWS;
    constexpr int TILES   = N / 64;
    constexpr int NKT     = TILES / SPLIT;
    constexpr int NKS     = QREG ? (Cc / 32) : 1;
    constexpr int NGRP    = (KC + KGRP - 1) / KGRP;
    constexpr int G       = 4 / CSPLIT;
    constexpr int QCH     = BROWS * 64;
    constexpr int QOFF    = KGRP * 4096;
    constexpr int KQEND   = QOFF + KGRP * QCH;
    constexpr int REGION  = QREG ? (SLABS * 4096)
                                 : (KQEND > SLABS * 4096 ? KQEND : SLABS * 4096);

    const int tid  = threadIdx.x;
    const int lane = tid & 63;
    const int w    = tid >> 6;
    const int l15  = lane & 15;
    const int quad = lane >> 4;

    const int bq = bid / SPLIT;
    const int sp = bid % SPLIT;
    const int b  = bq / QB;
    const int qb = bq % QB;
    const int ls  = w / CSPLIT;
    const int ch2 = w % CSPLIT;
    const int i0 = qb * BROWS + ls * 16;
    const long po = (long)(b * (N / 16) + qb * STRIPES + ls) * SPLIT + sp;
    ushort_t* Pw = smem + REGION + w * 1152;

    half8 qf[NKS];
    if constexpr (QREG) {
        const ushort_t* q1 = Qh + ((long)(b * N + i0 + l15)) * Cc + quad * 8;
#pragma unroll
        for (int ks = 0; ks < NKS; ++ks) qf[ks] = ldh(q1 + ks * 32);
    }

    float m_r[4], l_l[4], mw = -1e30f;
    f32x4 Mac[CTCW], Sac[CTCW];
#pragma unroll
    for (int r = 0; r < 4; ++r) { m_r[r] = -1e30f; l_l[r] = 0.f; }
#pragma unroll
    for (int ct = 0; ct < CTCW; ++ct)
#pragma unroll
        for (int r = 0; r < 4; ++r) { Mac[ct][r] = 0.f; Sac[ct][r] = 0.f; }

    for (int kt = sp * NKT; kt < sp * NKT + NKT; ++kt) {
        const long krow = (long)b * N + kt * 64;

        f32x4 S[4];
#pragma unroll
        for (int ct = 0; ct < 4; ++ct)
#pragma unroll
            for (int r = 0; r < 4; ++r) S[ct][r] = 0.f;

#pragma unroll
        for (int grp = 0; grp < NGRP; ++grp) {
            const int g0 = grp * KGRP;
            const int gn = (KC - g0 < KGRP) ? (KC - g0) : KGRP;
            __syncthreads();
#pragma unroll
            for (int j = 0; j < KGRP; ++j) if (j < gn) {
                stage64_async(Kh, krow, Cc, (g0 + j) * 64, smem + j * 4096, tid);
                if constexpr (!QREG)
                    stageQ_async<BROWS>(Qh, (long)b * N + qb * BROWS, Cc, (g0 + j) * 64,
                                        smem + QOFF + j * QCH, tid);
            }
            __syncthreads();
#pragma unroll
            for (int j = 0; j < KGRP; ++j) if (j < gn) {
                if (((g0 + j) % CSPLIT) == ch2) {
#pragma unroll
                    for (int ks = 0; ks < 2; ++ks) {
                        half8 a;
                        if constexpr (QREG) a = qf[(g0 + j) * 2 + ks];
                        else a = ldsw(smem + QOFF + j * QCH, ls * 16 + l15, ks * 32 + quad * 8);
#pragma unroll
                        for (int ct = 0; ct < 4; ++ct) {
                            half8 bf = ldsw(smem + j * 4096, ct * 16 + l15, ks * 32 + quad * 8);
                            S[ct] = MFMAH(a, bf, S[ct]);
                        }
                    }
                }
            }
        }

        if constexpr (CSPLIT > 1) {
            float* sred = (float*)smem;
            __syncthreads();
#pragma unroll
            for (int ct = 0; ct < 4; ++ct)
                *(f32x4*)&sred[(w * 4 + ct) * 256 + lane * 4] = S[ct];
            __syncthreads();
#pragma unroll
            for (int p = 0; p < 4; ++p) {
                if (p == w) continue;
                if ((p / CSPLIT) != ls) continue;
#pragma unroll
                for (int ct = 0; ct < 4; ++ct) {
                    f32x4 t = *(const f32x4*)&sred[(p * 4 + ct) * 256 + lane * 4];
                    S[ct] = S[ct] + t;
                }
            }
        }

        float tmax = S[0][0];
#pragma unroll
        for (int ct = 0; ct < 4; ++ct)
#pragma unroll
            for (int r = 0; r < 4; ++r) tmax = fmaxf(tmax, S[ct][r]);
#pragma unroll
        for (int off = 1; off <= 32; off <<= 1)
            tmax = fmaxf(tmax, __shfl_xor(tmax, off, 64));

        if (tmax > mw + 14.4269504f) {
            float rm[4];
#pragma unroll
            for (int r = 0; r < 4; ++r)
                rm[r] = fmaxf(fmaxf(S[0][r], S[1][r]), fmaxf(S[2][r], S[3][r]));
#pragma unroll
            for (int off = 1; off <= 8; off <<= 1)
#pragma unroll
                for (int r = 0; r < 4; ++r)
                    rm[r] = fmaxf(rm[r], __shfl_xor(rm[r], off, 64));
#pragma unroll
            for (int r = 0; r < 4; ++r) {
                float mn = fmaxf(m_r[r], rm[r]);
                float corr = exp2f(m_r[r] - mn);
                m_r[r] = mn;
                l_l[r] *= corr;
#pragma unroll
                for (int ct = 0; ct < CTCW; ++ct) { Mac[ct][r] *= corr; Sac[ct][r] *= corr; }
            }
            float t = fminf(fminf(m_r[0], m_r[1]), fminf(m_r[2], m_r[3]));
            t = fminf(t, __shfl_xor(t, 16, 64));
            t = fminf(t, __shfl_xor(t, 32, 64));
            mw = t;
        }

#pragma unroll
        for (int ct = 0; ct < 4; ++ct)
#pragma unroll
            for (int r = 0; r < 4; ++r) {
                float p = exp2f(S[ct][r] - m_r[r]);
                l_l[r] += p;
                Pw[(quad * 4 + r) * 72 + ct * 16 + l15] = f16_bits(p);
            }

        half8 pf0 = ldh(Pw + l15 * 72 + 0  + quad * 8);
        half8 pf1 = ldh(Pw + l15 * 72 + 32 + quad * 8);

#pragma unroll
        for (int g = 0; g < VCW; g += G) {
            __syncthreads();
#pragma unroll
            for (int s = 0; s < 4; ++s) {
                const int h = s / G, j = s % G;
                stage64_async(Vth, (long)b * C + (h * VCW + g + j) * 64, N, kt * 64,
                              smem + s * 4096, tid);
            }
            __syncthreads();
#pragma unroll
            for (int ks = 0; ks < 2; ++ks) {
                half8 pf = ks ? pf1 : pf0;
#pragma unroll
                for (int j = 0; j < G; ++j)
#pragma unroll
                    for (int ct = 0; ct < 4; ++ct) {
                        half8 vh = ldsw(smem + (ch2 * G + j) * 4096,
                                        ct * 16 + l15, ks * 32 + quad * 8);
                        half8 uh = vh * vh;
                        const int ci = (g + j) * 4 + ct;
                        Mac[ci] = MFMAH(pf, vh, Mac[ci]);
                        Sac[ci] = MFMAH(pf, uh, Sac[ci]);
                    }
            }
        }
    }

#pragma unroll
    for (int off = 1; off <= 8; off <<= 1)
#pragma unroll
        for (int r = 0; r < 4; ++r) l_l[r] += __shfl_xor(l_l[r], off, 64);

    if (ch2 == 0 && l15 == 0) {
#pragma unroll
        for (int r = 0; r < 4; ++r) {
            Pmo[po * 16 + quad * 4 + r] = m_r[r];
            Plo[po * 16 + quad * 4 + r] = l_l[r];
        }
    }
    const int chb = ch2 * (C / CSPLIT);
#pragma unroll
    for (int ct = 0; ct < CTCW; ++ct)
#pragma unroll
        for (int r = 0; r < 4; ++r) {
            long idx = (po * 16 + quad * 4 + r) * C + chb + ct * 16 + l15;
            PMo[idx] = Mac[ct][r];
            PSo[idx] = Sac[ct][r];
        }
}

// fused s3+s4 flash: one launch (s4 SPLIT=2, private partials in arena tail)
__global__ void __launch_bounds__(256, 2) flash34(
    const ushort_t* __restrict__ Qh3, const ushort_t* __restrict__ Kh3,
    const ushort_t* __restrict__ Vth3,
    float* __restrict__ Pm3, float* __restrict__ Pl3,
    float* __restrict__ PM3, float* __restrict__ PS3,
    const ushort_t* __restrict__ Qh4, const ushort_t* __restrict__ Kh4,
    const ushort_t* __restrict__ Vth4,
    float* __restrict__ Pm4, float* __restrict__ Pl4,
    float* __restrict__ PM4, float* __restrict__ PS4)
{
    __shared__ __align__(16) ushort_t smem[35328];
    if ((int)blockIdx.x < 512)
        flash_body<960, 512, 1024, 2, false, 4, 5, 5>(
            Qh3, Kh3, Vth3, Pm3, Pl3, PM3, PS3, smem, (int)blockIdx.x);
    else
        flash_body<1472, 512, 256, 4, false, 2, 6, 6>(
            Qh4, Kh4, Vth4, Pm4, Pl4, PM4, PS4, smem, (int)blockIdx.x - 512);
}

// ---------------------------------------------------------------------------
// Combine body (merge SPLIT partials, inline content stats, fused MSE).
// ---------------------------------------------------------------------------
template<int C, int SPLIT>
__device__ __forceinline__ void combine_body(
    const float* __restrict__ Pm, const float* __restrict__ Pl,
    const float* __restrict__ PM, const float* __restrict__ PS,
    const float* __restrict__ CT, const float* __restrict__ CS,
    const float* __restrict__ csum, const float* __restrict__ csq,
    float invN, float* __restrict__ loss, int N, int pi, float* shm)
{
    constexpr int CL4 = C / 4;
    float (*wS)[16] = (float(*)[16])shm;
    float* invL = shm + SPLIT * 16;
    float* red  = invL + 16;
    const int nb = N / 16;
    const int b  = pi / nb;
    const long g0 = (long)b * N + (long)(pi % nb) * 16;
    const int tid = threadIdx.x;

    if (tid < 16) {
        float m = -1e30f;
#pragma unroll
        for (int s = 0; s < SPLIT; ++s)
            m = fmaxf(m, Pm[((long)pi * SPLIT + s) * 16 + tid]);
        float L = 0.f;
#pragma unroll
        for (int s = 0; s < SPLIT; ++s) {
            float e = exp2f(Pm[((long)pi * SPLIT + s) * 16 + tid] - m);
            wS[s][tid] = e;
            L = fmaf(e, Pl[((long)pi * SPLIT + s) * 16 + tid], L);
        }
        invL[tid] = 1.f / L;
    }
    __syncthreads();

    float acc = 0.f;
    for (int v = tid; v < 4 * C; v += 256) {
        const int r  = v / CL4;
        const int c0 = (v - r * CL4) * 4;
        const long q0 = (((long)pi * SPLIT) * 16 + r) * C + c0;
        float4 Ms = {0.f, 0.f, 0.f, 0.f}, Ss = {0.f, 0.f, 0.f, 0.f};
#pragma unroll
        for (int s = 0; s < SPLIT; ++s) {
            const float ws_ = wS[s][r];
            const float4 pm = *(const float4*)&PM[q0 + (long)s * 16 * C];
            const float4 ps = *(const float4*)&PS[q0 + (long)s * 16 * C];
            Ms.x = fmaf(ws_, pm.x, Ms.x); Ms.y = fmaf(ws_, pm.y, Ms.y);
            Ms.z = fmaf(ws_, pm.z, Ms.z); Ms.w = fmaf(ws_, pm.w, Ms.w);
            Ss.x = fmaf(ws_, ps.x, Ss.x); Ss.y = fmaf(ws_, ps.y, Ss.y);
            Ss.z = fmaf(ws_, ps.z, Ss.z); Ss.w = fmaf(ws_, ps.w, Ss.w);
        }
        const float iL = invL[r];
        const float4 ctv = *(const float4*)&CT[(g0 + r) * C + c0];
        const float4 csv = *(const float4*)&CS[(g0 + r) * C + c0];
        const float4 cs4 = *(const float4*)&csum[b * C + c0];
        const float4 cq4 = *(const float4*)&csq[b * C + c0];
#pragma unroll
        for (int e = 0; e < 4; ++e) {
            const float Msx = (&Ms.x)[e] * iL;
            const float S2  = (&Ss.x)[e] * iL - Msx * Msx;
            const float Sx  = sqrtf(fmaxf(S2, EPS_VAR));
            const float cm  = (&cs4.x)[e] * invN;
            const float cr  = rsqrtf((&cq4.x)[e] * invN - cm * cm + EPS_NORM);
            const float nc  = ((&ctv.x)[e] - cm) * cr;
            const float d   = (&csv.x)[e] - (Sx * nc + Msx);
            acc = fmaf(d, d, acc);
        }
    }
#pragma unroll
    for (int off = 1; off <= 32; off <<= 1) acc += __shfl_xor(acc, off, 64);
    if ((tid & 63) == 0) red[tid >> 6] = acc;
    __syncthreads();
    if (tid == 0) atomicAdd(loss, red[0] + red[1] + red[2] + red[3]);
}

// ---------------------------------------------------------------------------
// mid_fused: combine2 (1024) || prep3 (2048+512) || prep4 (512+128)
// ---------------------------------------------------------------------------
struct MidP {
    const float *Pm, *Pl, *PM, *PS, *CT, *CS, *csum, *csq;
    float* loss;
    const float *q3x, *q3s, *q3q, *k3x, *k3s, *k3q, *v3x;
    ushort_t *qh3, *kh3, *vt3;
    const float *q4x, *q4s, *q4q, *k4x, *k4s, *k4q, *v4x;
    ushort_t *qh4, *kh4, *vt4;
};
__global__ void __launch_bounds__(256) mid_fused(MidP P)
{
    __shared__ __align__(16) ushort_t lbuf[4608];
    int bx = blockIdx.x;
    if (bx < 1024) {
        combine_body<256, 2>(P.Pm, P.Pl, P.PM, P.PS, P.CT, P.CS, P.csum, P.csq,
                             1.0f / 4096.0f, P.loss, 4096, bx, (float*)lbuf);
    } else if (bx < 3072) {
        norm_quad(bx - 1024, P.q3x, P.q3s, P.q3q, P.k3x, P.k3s, P.k3q,
                  P.qh3, P.kh3, 1024, 960, 1.0f / 1024.0f);
    } else if (bx < 3584) {
        vtile(bx - 3072, P.v3x, P.vt3, 1024, 512, lbuf);
    } else if (bx < 4096) {
        norm_quad(bx - 3584, P.q4x, P.q4s, P.q4q, P.k4x, P.k4s, P.k4q,
                  P.qh4, P.kh4, 256, 1472, 1.0f / 256.0f);
    } else {
        vtile(bx - 4096, P.v4x, P.vt4, 256, 512, lbuf);
    }
}

// ---------------------------------------------------------------------------
// combine34_final: combine3 (256, SPLIT=4) || combine4 (64, SPLIT=2) + fold
// ---------------------------------------------------------------------------
struct C34P {
    const float *Pm3, *Pl3, *PM3, *PS3, *CT3, *CS3, *c3s, *c3q;
    const float *Pm4, *Pl4, *PM4, *PS4, *CT4, *CS4, *c4s, *c4q;
    float* lossp;      // [0..2] partial losses, [3] = completion counter bits
    float* out;
    float s0, s1, s2;
};
__global__ void __launch_bounds__(256) combine34_final(C34P P)
{
    __shared__ float shm[4 * 16 + 20];
    int bx = blockIdx.x;
    if (bx < 256)
        combine_body<512, 4>(P.Pm3, P.Pl3, P.PM3, P.PS3, P.CT3, P.CS3, P.c3s, P.c3q,
                             1.0f / 1024.0f, &P.lossp[1], 1024, bx, shm);
    else
        combine_body<512, 2>(P.Pm4, P.Pl4, P.PM4, P.PS4, P.CT4, P.CS4, P.c4s, P.c4q,
                             1.0f / 256.0f, &P.lossp[2], 256, bx - 256, shm);
    __threadfence();
    if (threadIdx.x == 0) {
        unsigned old = atomicAdd((unsigned*)&P.lossp[3], 1u);
        if (old == 319u) {
            float l0 = atomicAdd(&P.lossp[0], 0.0f);
            float l1 = atomicAdd(&P.lossp[1], 0.0f);
            float l2 = atomicAdd(&P.lossp[2], 0.0f);
            P.out[0] = l0 * P.s0 + l1 * P.s1 + l2 * P.s2;
        }
    }
}

// ---------------------------------------------------------------------------
// Fallback scalar flash kernel (only if ws_size too small)
// ---------------------------------------------------------------------------
template<int CCL, int CL, int NQ>
__global__ void __launch_bounds__(256) flash_aat(
    const float* __restrict__ Q, const float* __restrict__ K, const float* __restrict__ V,
    const float* __restrict__ CT, const float* __restrict__ CS,
    const float* __restrict__ qmean, const float* __restrict__ qrstd,
    const float* __restrict__ kmean, const float* __restrict__ krstd,
    const float* __restrict__ cmean, const float* __restrict__ crstd,
    float* __restrict__ loss, int N)
{
    constexpr int CC   = CCL * 64;
    constexpr int C    = CL * 64;
    constexpr int ROWS = 4 * NQ;
    const int lane = threadIdx.x & 63;
    const int wave = threadIdx.x >> 6;
    const int rowBlocks = N / ROWS;
    const int b  = blockIdx.x / rowBlocks;
    const int rb = blockIdx.x % rowBlocks;
    const int i0 = rb * ROWS + wave * NQ;

    float kmu[CCL], krs[CCL];
#pragma unroll
    for (int t = 0; t < CCL; ++t) {
        int ch = lane + 64 * t;
        kmu[t] = kmean[b * CC + ch];
        krs[t] = krstd[b * CC + ch];
    }
    float q[NQ][CCL];
#pragma unroll
    for (int qi = 0; qi < NQ; ++qi) {
        long base = (long)(b * N + i0 + qi) * CC;
#pragma unroll
        for (int t = 0; t < CCL; ++t) {
            int ch = lane + 64 * t;
            q[qi][t] = (Q[base + ch] - qmean[b * CC + ch]) * qrstd[b * CC + ch];
        }
    }
    float mval[NQ], lsum[NQ];
    float Macc[NQ][CL], Sacc[NQ][CL];
#pragma unroll
    for (int qi = 0; qi < NQ; ++qi) {
        mval[qi] = -1e30f; lsum[qi] = 0.f;
#pragma unroll
        for (int t = 0; t < CL; ++t) { Macc[qi][t] = 0.f; Sacc[qi][t] = 0.f; }
    }
    for (int j = 0; j < N; ++j) {
        long kb = (long)(b * N + j) * CC;
        float dot[NQ];
#pragma unroll
        for (int qi = 0; qi < NQ; ++qi) dot[qi] = 0.f;
#pragma unroll
        for (int t = 0; t < CCL; ++t) {
            float kv = (K[kb + lane + 64 * t] - kmu[t]) * krs[t];
#pragma unroll
            for (int qi = 0; qi < NQ; ++qi) dot[qi] = fmaf(q[qi][t], kv, dot[qi]);
        }
#pragma unroll
        for (int off = 32; off > 0; off >>= 1)
#pragma unroll
            for (int qi = 0; qi < NQ; ++qi) dot[qi] += __shfl_xor(dot[qi], off, 64);
        long vb = (long)(b * N + j) * C;
        float vv[CL];
#pragma unroll
        for (int t = 0; t < CL; ++t) vv[t] = V[vb + lane + 64 * t];
#pragma unroll
        for (int qi = 0; qi < NQ; ++qi) {
            float s = dot[qi];
            float p;
            if (s > mval[qi]) {
                float cr2 = __expf(mval[qi] - s);
                lsum[qi] *= cr2;
#pragma unroll
                for (int t = 0; t < CL; ++t) { Macc[qi][t] *= cr2; Sacc[qi][t] *= cr2; }
                mval[qi] = s; p = 1.f;
            } else p = __expf(s - mval[qi]);
            lsum[qi] += p;
#pragma unroll
            for (int t = 0; t < CL; ++t) {
                float pv = p * vv[t];
                Macc[qi][t] += pv;
                Sacc[qi][t] = fmaf(pv, vv[t], Sacc[qi][t]);
            }
        }
    }
    float acc = 0.f;
#pragma unroll
    for (int qi = 0; qi < NQ; ++qi) {
        float inv_l = 1.f / lsum[qi];
        long base = (long)(b * N + i0 + qi) * C;
#pragma unroll
        for (int t = 0; t < CL; ++t) {
            int ch = lane + 64 * t;
            float M  = Macc[qi][t] * inv_l;
            float S2 = Sacc[qi][t] * inv_l - M * M;
            float S  = sqrtf(fmaxf(S2, EPS_VAR));
            float nc = (CT[base + ch] - cmean[b * C + ch]) * crstd[b * C + ch];
            float d  = CS[base + ch] - (S * nc + M);
            acc = fmaf(d, d, acc);
        }
    }
#pragma unroll
    for (int off = 32; off > 0; off >>= 1) acc += __shfl_xor(acc, off, 64);
    if (lane == 0) atomicAdd(loss, acc);
}

__global__ void combine_loss(const float* __restrict__ lp, float* __restrict__ out,
                             float s0, float s1, float s2)
{
    out[0] = lp[0] * s0 + lp[1] * s1 + lp[2] * s2;
}

// ---------------------------------------------------------------------------
extern "C" void kernel_launch(void* const* d_in, const int* in_sizes, int n_in,
                              void* d_out, int out_size, void* d_ws, size_t ws_size,
                              hipStream_t stream)
{
    const float* cs2 = (const float*)d_in[0];
    const float* c2  = (const float*)d_in[1];
    const float* s2v = (const float*)d_in[2];
    const float* cc2 = (const float*)d_in[3];
    const float* sc2 = (const float*)d_in[4];
    const float* cs3 = (const float*)d_in[5];
    const float* c3  = (const float*)d_in[6];
    const float* s3v = (const float*)d_in[7];
    const float* cc3 = (const float*)d_in[8];
    const float* sc3 = (const float*)d_in[9];
    const float* cs4 = (const float*)d_in[10];
    const float* c4  = (const float*)d_in[11];
    const float* s4v = (const float*)d_in[12];
    const float* cc4 = (const float*)d_in[13];
    const float* sc4 = (const float*)d_in[14];

    const int B = 4;
    float* ws = (float*)d_ws;
    size_t fo = 0;
    auto allocF = [&](size_t n) { float* p = ws + fo; fo += n; return p; };

    float* lossp = allocF(4);                  // [3] doubles as completion counter
    float* c2m = allocF(B * 256);  float* c2r = allocF(B * 256);
    float* q2m = allocF(B * 448);  float* q2r = allocF(B * 448);
    float* k2m = allocF(B * 448);  float* k2r = allocF(B * 448);
    float* c3m = allocF(B * 512);  float* c3r = allocF(B * 512);
    float* q3m = allocF(B * 960);  float* q3r = allocF(B * 960);
    float* k3m = allocF(B * 960);  float* k3r = allocF(B * 960);
    float* c4m = allocF(B * 512);  float* c4r = allocF(B * 512);
    float* q4m = allocF(B * 1472); float* q4r = allocF(B * 1472);
    float* k4m = allocF(B * 1472); float* k4r = allocF(B * 1472);
    size_t zeroBytes = fo * sizeof(float);

    float* Pm = allocF(32768);
    float* Pl = allocF(32768);
    float* PM = allocF(8388608);
    float* PS = allocF(8388608);

    size_t arenaOff = ((fo * 4 + 15) & ~(size_t)15) / 2;
    ushort_t* arena = (ushort_t*)d_ws + arenaOff;
    const size_t arenaShorts = 18874400;
    size_t need = arenaOff * 2 + arenaShorts * 2;
    const bool fast = (ws_size >= need);

    hipMemsetAsync(d_ws, 0, zeroBytes, stream);

    // ---- fused stats (1 launch, vectorized, raw sums) ----
    StatJobs4 SJ;
    int statBlocks = 0;
    {
        const float* xs[9] = {c2, cc2, sc2, c3, cc3, sc3, c4, cc4, sc4};
        float* sms[9] = {c2m, q2m, k2m, c3m, q3m, k3m, c4m, q4m, k4m};
        float* sqs[9] = {c2r, q2r, k2r, c3r, q3r, k3r, c4r, q4r, k4r};
        const int Ns[9]  = {4096, 4096, 4096, 1024, 1024, 1024, 256, 256, 256};
        const int Cns[9] = {256, 448, 448, 512, 960, 960, 512, 1472, 1472};
        for (int j = 0; j < 9; ++j) {
            int cG = (Cns[j] + 255) / 256;
            int nG = (Ns[j] + 127) / 128;
            SJ.x[j] = xs[j]; SJ.sm[j] = sms[j]; SJ.sq[j] = sqs[j];
            SJ.N[j] = Ns[j]; SJ.Cn[j] = Cns[j]; SJ.cG[j] = cG; SJ.nG[j] = nG;
            SJ.base[j] = statBlocks;
            statBlocks += B * cG * nG;
        }
    }
    hipLaunchKernelGGL(stat_partial_all, dim3(statBlocks), dim3(256), 0, stream, SJ);

    if (fast) {
        ushort_t* qh2 = arena;
        ushort_t* kh2 = qh2 + (size_t)B * 4096 * 448;
        ushort_t* vh2 = kh2 + (size_t)B * 4096 * 448;
        ushort_t* qh3 = arena;
        ushort_t* kh3 = qh3 + (size_t)B * 1024 * 960;
        ushort_t* vh3 = kh3 + (size_t)B * 1024 * 960;
        ushort_t* qh4 = vh3 + (size_t)B * 1024 * 512;
        ushort_t* kh4 = qh4 + (size_t)B * 256 * 1472;
        ushort_t* vh4 = kh4 + (size_t)B * 256 * 1472;
        size_t o34 = (size_t)B * 1024 * 960 * 2 + (size_t)B * 1024 * 512
                   + (size_t)B * 256 * 1472 * 2 + (size_t)B * 256 * 512;
        float* PM4 = (float*)(arena + o34);
        float* PS4 = PM4 + 1048576;
        float* Pm4 = Pm + 16384;
        float* Pl4 = Pl + 16384;

        // 1) prep scale 2
        hipLaunchKernelGGL(prep2, dim3(8192 + 1024), dim3(256), 0, stream,
                           cc2, q2m, q2r, sc2, k2m, k2r, qh2, kh2, s2v, vh2);
        // 2) flash scale 2
        hipLaunchKernelGGL(flash_pipe, dim3(512), dim3(256), 0, stream,
                           qh2, kh2, vh2, Pm, Pl, PM, PS);
        // 3) combine2 || prep scales 3+4
        {
            MidP MP;
            MP.Pm = Pm; MP.Pl = Pl; MP.PM = PM; MP.PS = PS;
            MP.CT = c2; MP.CS = cs2; MP.csum = c2m; MP.csq = c2r;
            MP.loss = &lossp[0];
            MP.q3x = cc3; MP.q3s = q3m; MP.q3q = q3r;
            MP.k3x = sc3; MP.k3s = k3m; MP.k3q = k3r; MP.v3x = s3v;
            MP.qh3 = qh3; MP.kh3 = kh3; MP.vt3 = vh3;
            MP.q4x = cc4; MP.q4s = q4m; MP.q4q = q4r;
            MP.k4x = sc4; MP.k4s = k4m; MP.k4q = k4r; MP.v4x = s4v;
            MP.qh4 = qh4; MP.kh4 = kh4; MP.vt4 = vh4;
            hipLaunchKernelGGL(mid_fused, dim3(4224), dim3(256), 0, stream, MP);
        }
        // 4) flash scales 3+4 fused
        hipLaunchKernelGGL(flash34, dim3(512 + 128), dim3(256), 0, stream,
                           qh3, kh3, vh3, Pm, Pl, PM, PS,
                           qh4, kh4, vh4, Pm4, Pl4, PM4, PS4);
        // 5) combine3 || combine4 + final loss fold
        {
            C34P CP;
            CP.Pm3 = Pm; CP.Pl3 = Pl; CP.PM3 = PM; CP.PS3 = PS;
            CP.CT3 = c3; CP.CS3 = cs3; CP.c3s = c3m; CP.c3q = c3r;
            CP.Pm4 = Pm4; CP.Pl4 = Pl4; CP.PM4 = PM4; CP.PS4 = PS4;
            CP.CT4 = c4; CP.CS4 = cs4; CP.c4s = c4m; CP.c4q = c4r;
            CP.lossp = lossp; CP.out = (float*)d_out;
            CP.s0 = 1.0f / (4.0f * 4096.0f * 256.0f);
            CP.s1 = 1.0f / (4.0f * 1024.0f * 512.0f);
            CP.s2 = 1.0f / (4.0f * 256.0f * 512.0f);
            hipLaunchKernelGGL(combine34_final, dim3(256 + 64), dim3(256), 0, stream, CP);
        }
    } else {
        // fallback: finalize stats then scalar flash
        {
            FinJobs FJ;
            float* sms[9] = {c2m, q2m, k2m, c3m, q3m, k3m, c4m, q4m, k4m};
            float* sqs[9] = {c2r, q2r, k2r, c3r, q3r, k3r, c4r, q4r, k4r};
            const int Ns[9]  = {4096, 4096, 4096, 1024, 1024, 1024, 256, 256, 256};
            const int Cns[9] = {256, 448, 448, 512, 960, 960, 512, 1472, 1472};
            int fb = 0;
            for (int j = 0; j < 9; ++j) {
                FJ.sm[j] = sms[j]; FJ.sq[j] = sqs[j]; FJ.base[j] = fb;
                FJ.invN[j] = 1.0f / (float)Ns[j];
                fb += B * Cns[j];
            }
            FJ.total = fb;
            hipLaunchKernelGGL(stat_finalize_all, dim3((fb + 255) / 256), dim3(256), 0, stream, FJ);
        }
        hipLaunchKernelGGL((flash_aat<7, 4, 4>), dim3(B * 4096 / 16), dim3(256), 0, stream,
                           cc2, sc2, s2v, c2, cs2, q2m, q2r, k2m, k2r, c2m, c2r, &lossp[0], 4096);
        hipLaunchKernelGGL((flash_aat<15, 8, 2>), dim3(B * 1024 / 8), dim3(256), 0, stream,
                           cc3, sc3, s3v, c3, cs3, q3m, q3r, k3m, k3r, c3m, c3r, &lossp[1], 1024);
        hipLaunchKernelGGL((flash_aat<23, 8, 2>), dim3(B * 256 / 8), dim3(256), 0, stream,
                           cc4, sc4, s4v, c4, cs4, q4m, q4r, k4m, k4r, c4m, c4r, &lossp[2], 256);
        hipLaunchKernelGGL(combine_loss, dim3(1), dim3(1), 0, stream,
                           lossp, (float*)d_out,
                           1.0f / (4.0f * 4096.0f * 256.0f),
                           1.0f / (4.0f * 1024.0f * 512.0f),
                           1.0f / (4.0f * 256.0f * 512.0f));
    }
}